// Round 13
// baseline (247.219 us; speedup 1.0000x reference)
//
#include <hip/hip_runtime.h>
#include <math.h>

#define DMODEL 256
#define NHEAD 8
#define NLVL 3
#define NPTS 4
#define HDIM 32
#define QLEN 10000
#define BATCH 4
#define NQ (BATCH * QLEN)

typedef __attribute__((ext_vector_type(8))) short bf16x8;
typedef __attribute__((ext_vector_type(4))) float f32x4;

__device__ __forceinline__ float tanh_fast(float x)
{
    const float ax = fabsf(x);
    const float e  = __expf(-2.f * ax);
    const float t  = (1.f - e) / (1.f + e);
    return copysignf(t, x);
}

__device__ __forceinline__ unsigned short f2bf(float f)
{
    unsigned int u = __float_as_uint(f);
    u = (u + 0x7FFFu + ((u >> 16) & 1u)) >> 16;
    return (unsigned short)u;
}

__device__ __forceinline__ float bf2f(unsigned short s)
{
    return __uint_as_float(((unsigned int)s) << 16);
}

// ---------------------------------------------------------------------------
// K0: weight prep (once).
// ---------------------------------------------------------------------------
__global__ __launch_bounds__(256) void wprep_kernel(
    const float* __restrict__ Woff, const float* __restrict__ Wattn,
    const float* __restrict__ Wout, const float* __restrict__ Wval,
    unsigned short* __restrict__ WTh, unsigned short* __restrict__ WTl,
    unsigned short* __restrict__ WoT,
    unsigned short* __restrict__ WvTh, unsigned short* __restrict__ WvTl)
{
    const int k = threadIdx.x;
    const int n = blockIdx.x;
    if (n < 288) {
        const float w = (n < 192) ? Woff[(size_t)k * 192 + n]
                                  : Wattn[(size_t)k * 96 + (n - 192)];
        const unsigned short hi = f2bf(w);
        WTh[(size_t)n * 256 + k] = hi;
        WTl[(size_t)n * 256 + k] = f2bf(w - bf2f(hi));
    } else if (n < 544) {
        const int nn = n - 288;
        WoT[(size_t)nn * 256 + k] = f2bf(Wout[(size_t)k * 256 + nn]);
    } else {
        const int nn = n - 544;
        const float w = Wval[(size_t)k * 256 + nn];
        const unsigned short hi = f2bf(w);
        WvTh[(size_t)nn * 256 + k] = hi;
        WvTl[(size_t)nn * 256 + k] = f2bf(w - bf2f(hi));
    }
}

// ---------------------------------------------------------------------------
// K1: value projection via bf16 MFMA (validated R10/R11).  Output HEAD-MAJOR
// v[b][h][pos][32].
// ---------------------------------------------------------------------------
__global__ __launch_bounds__(256) void vproj_kernel(
    const float* __restrict__ feat0, const float* __restrict__ feat1,
    const float* __restrict__ feat2,
    const unsigned short* __restrict__ WvTh, const unsigned short* __restrict__ WvTl,
    const float* __restrict__ bv,
    unsigned short* __restrict__ v0, unsigned short* __restrict__ v1,
    unsigned short* __restrict__ v2)
{
    __shared__ short As[32 * 64 * 8];   // [kc][pos][8] = 32 KB

    const int bx = blockIdx.x;
    const int b  = blockIdx.y;

    const float* feat;
    unsigned short* vout;
    int HW, pos0;
    if (bx < 157)      { feat = feat0; vout = v0; HW = 10000; pos0 = bx * 64; }
    else if (bx < 197) { feat = feat1; vout = v1; HW = 2500;  pos0 = (bx - 157) * 64; }
    else               { feat = feat2; vout = v2; HW = 625;   pos0 = (bx - 197) * 64; }

    const int tid  = threadIdx.x;
    const int wv   = tid >> 6;
    const int lane = tid & 63;
    const int c    = lane & 15;
    const int g    = lane >> 4;

    const int sp = tid & 63;
    const int kb = (tid >> 6) * 64;
    const bool pv = (pos0 + sp) < HW;
    const float* fcol = feat + (size_t)b * DMODEL * HW + pos0 + sp;

#pragma unroll
    for (int i = 0; i < 8; ++i) {
        short h8[8];
#pragma unroll
        for (int j = 0; j < 8; ++j) {
            const int k = kb + i * 8 + j;
            const float f = pv ? fcol[(size_t)k * HW] : 0.f;
            h8[j] = (short)f2bf(f);
        }
        *(bf16x8*)&As[((size_t)(kb / 8 + i) * 64 + sp) * 8] = *(bf16x8*)h8;
    }
    __syncthreads();

    f32x4 acc[4][4];
#pragma unroll
    for (int mt = 0; mt < 4; ++mt)
#pragma unroll
        for (int nt = 0; nt < 4; ++nt)
            acc[mt][nt] = (f32x4){0.f, 0.f, 0.f, 0.f};

#pragma unroll
    for (int ks = 0; ks < 8; ++ks) {
        bf16x8 a[4];
#pragma unroll
        for (int mt = 0; mt < 4; ++mt)
            a[mt] = *(const bf16x8*)&As[((size_t)(ks * 4 + g) * 64 + mt * 16 + c) * 8];
        bf16x8 bh[4], bl[4];
#pragma unroll
        for (int nt = 0; nt < 4; ++nt) {
            const size_t off = (size_t)(wv * 64 + nt * 16 + c) * 256 + ks * 32 + 8 * g;
            bh[nt] = *(const bf16x8*)(WvTh + off);
            bl[nt] = *(const bf16x8*)(WvTl + off);
        }
#pragma unroll
        for (int mt = 0; mt < 4; ++mt)
#pragma unroll
            for (int nt = 0; nt < 4; ++nt) {
                acc[mt][nt] = __builtin_amdgcn_mfma_f32_16x16x32_bf16(
                    a[mt], bh[nt], acc[mt][nt], 0, 0, 0);
                acc[mt][nt] = __builtin_amdgcn_mfma_f32_16x16x32_bf16(
                    a[mt], bl[nt], acc[mt][nt], 0, 0, 0);
            }
    }

    unsigned short* vb = vout + (size_t)b * NHEAD * HW * 32;
#pragma unroll
    for (int nt = 0; nt < 4; ++nt) {
        const int col  = wv * 64 + nt * 16 + c;
        const int hh   = col >> 5;
        const int cc   = col & 31;
        const float bias = bv[col];
#pragma unroll
        for (int mt = 0; mt < 4; ++mt) {
#pragma unroll
            for (int j = 0; j < 4; ++j) {
                const int p = mt * 16 + g * 4 + j;
                if (pos0 + p < HW)
                    vb[((size_t)hh * HW + pos0 + p) * 32 + cc] =
                        f2bf(acc[mt][nt][j] + bias);
            }
        }
    }
}

// ---------------------------------------------------------------------------
// K2: query-side GEMM ONLY (no epilogue).  32 rows/block (1250 blocks),
// 4 waves col-split (5/5/4/4 of 18 col-tiles), conflict-free subtile LDS
// (R12 layout).  LDS = 36.9 KB -> 4 blocks/CU.  Writes raw logits f32.
// ---------------------------------------------------------------------------
__global__ __launch_bounds__(256) void qgemm_kernel(
    const float* __restrict__ query,
    const unsigned short* __restrict__ WTh,
    float* __restrict__ logits)
{
    __shared__ __align__(16) short Bs[2 * 18 * 64 * 8];   // 36864 B

    const int tid  = threadIdx.x;
    const int wt   = tid >> 6;
    const int lane = tid & 63;
    const int c    = lane & 15;
    const int g    = lane >> 4;
    const int row0 = blockIdx.x * 32;

    // staging offsets (WTl contiguous after WTh at +288*256)
    int srco[9], dsto[9];
#pragma unroll
    for (int i = 0; i < 9; ++i) {
        const int ch  = tid + 256 * i;            // 0..2303
        const int hl  = ch >= 1152;
        const int rem = hl ? ch - 1152 : ch;
        const int col = rem >> 2;
        const int gg  = rem & 3;
        srco[i] = hl * (288 * 256) + col * 256 + gg * 8;
        dsto[i] = (hl * 1152 + (col >> 4) * 64 + gg * 16 + (col & 15)) * 8;
    }

    const float* qr[2];
#pragma unroll
    for (int t = 0; t < 2; ++t)
        qr[t] = query + (size_t)(row0 + t * 16 + c) * 256 + 8 * g;

    f32x4 acc[2][5];
#pragma unroll
    for (int t = 0; t < 2; ++t)
#pragma unroll
        for (int i = 0; i < 5; ++i) acc[t][i] = (f32x4){0.f, 0.f, 0.f, 0.f};

    for (int ks = 0; ks < 8; ++ks) {
#pragma unroll
        for (int i = 0; i < 9; ++i)
            *(bf16x8*)(Bs + dsto[i]) = *(const bf16x8*)(WTh + srco[i] + ks * 32);
        __syncthreads();

        bf16x8 a_hi[2], a_lo[2];
#pragma unroll
        for (int t = 0; t < 2; ++t) {
            const float4 q0 = *(const float4*)(qr[t] + ks * 32);
            const float4 q1 = *(const float4*)(qr[t] + ks * 32 + 4);
            const float av[8] = {q0.x, q0.y, q0.z, q0.w, q1.x, q1.y, q1.z, q1.w};
#pragma unroll
            for (int j = 0; j < 8; ++j) {
                const unsigned short hi = f2bf(av[j]);
                a_hi[t][j] = (short)hi;
                a_lo[t][j] = (short)f2bf(av[j] - bf2f(hi));
            }
        }

#pragma unroll
        for (int i = 0; i < 5; ++i) {
            const int nt = wt + 4 * i;
            if (nt < 18) {
                const bf16x8 b_hi = *(const bf16x8*)(Bs + (nt * 64 + g * 16 + c) * 8);
                const bf16x8 b_lo = *(const bf16x8*)(Bs + (1152 + nt * 64 + g * 16 + c) * 8);
#pragma unroll
                for (int t = 0; t < 2; ++t) {
                    acc[t][i] = __builtin_amdgcn_mfma_f32_16x16x32_bf16(
                        a_hi[t], b_hi, acc[t][i], 0, 0, 0);
                    acc[t][i] = __builtin_amdgcn_mfma_f32_16x16x32_bf16(
                        a_lo[t], b_hi, acc[t][i], 0, 0, 0);
                    acc[t][i] = __builtin_amdgcn_mfma_f32_16x16x32_bf16(
                        a_hi[t], b_lo, acc[t][i], 0, 0, 0);
                }
            }
        }
        __syncthreads();
    }

    // store raw logits (D rows = row0 + t*16 + 4g+j, col = nt*16 + c)
#pragma unroll
    for (int i = 0; i < 5; ++i) {
        const int nt = wt + 4 * i;
        if (nt < 18) {
            const int col = nt * 16 + c;
#pragma unroll
            for (int t = 0; t < 2; ++t)
#pragma unroll
                for (int j = 0; j < 4; ++j)
                    logits[(size_t)(row0 + t * 16 + 4 * g + j) * 288 + col] =
                        acc[t][i][j];
        }
    }
}

// ---------------------------------------------------------------------------
// K3: sampler with FUSED epilogue.  Block = (32 q, head h, batch b); wave =
// 8 q x 1 head; lane = (qd, ch-oct).  The 8 lanes of a group share (q,h):
// they load the 36 logits (broadcast), add biases, softmax + tanh in-register
// (bit-identical math to the old qparam epilogue), then bilinear-sample.
// ---------------------------------------------------------------------------
__global__ __launch_bounds__(256) void sample_kernel(
    const float* __restrict__ logits,
    const float* __restrict__ ref,
    const float* __restrict__ boff, const float* __restrict__ battn,
    const unsigned short* __restrict__ v0,
    const unsigned short* __restrict__ v1,
    const unsigned short* __restrict__ v2,
    unsigned short* __restrict__ outp)
{
    const int tid  = threadIdx.x;
    const int wv   = tid >> 6;
    const int lane = tid & 63;
    const int qd   = lane >> 3;
    const int co   = lane & 7;
    const int h    = blockIdx.y;
    const int b    = blockIdx.z;
    const int q    = blockIdx.x * 32 + wv * 8 + qd;
    if (q >= QLEN) return;
    const int qq   = b * QLEN + q;

    // ---- epilogue: logits -> sampling params (in f[36]) ----
    const float* lgq = logits + (size_t)qq * 288;
    float f[36];                       // first 24 hold offset logits, then x,y,aw
    float at[12];
#pragma unroll
    for (int u = 0; u < 6; ++u) {
        const float4 v4 = *(const float4*)(lgq + h * 24 + 4 * u);
        const float4 b4 = *(const float4*)(boff + h * 24 + 4 * u);
        f[4 * u + 0] = v4.x + b4.x; f[4 * u + 1] = v4.y + b4.y;
        f[4 * u + 2] = v4.z + b4.z; f[4 * u + 3] = v4.w + b4.w;
    }
#pragma unroll
    for (int u = 0; u < 3; ++u) {
        const float4 v4 = *(const float4*)(lgq + 192 + h * 12 + 4 * u);
        const float4 b4 = *(const float4*)(battn + h * 12 + 4 * u);
        at[4 * u + 0] = v4.x + b4.x; at[4 * u + 1] = v4.y + b4.y;
        at[4 * u + 2] = v4.z + b4.z; at[4 * u + 3] = v4.w + b4.w;
    }

    float m = at[0];
#pragma unroll
    for (int j = 1; j < 12; ++j) m = fmaxf(m, at[j]);
    float s = 0.f;
#pragma unroll
    for (int j = 0; j < 12; ++j) { at[j] = __expf(at[j] - m); s += at[j]; }
    const float inv = 1.f / s;

    const float refx = ref[(size_t)qq * 2 + 0];
    const float refy = ref[(size_t)qq * 2 + 1];

    // transform descending so writes at 3j don't clobber unread reads at 2j
#pragma unroll
    for (int j = 11; j >= 0; --j) {
        const int l = j >> 2;
        const float Wl = (l == 0) ? 100.f : (l == 1) ? 50.f : 25.f;
        const float ox = 0.5f * tanh_fast(f[2 * j + 0]);
        const float oy = 0.5f * tanh_fast(f[2 * j + 1]);
        f[3 * j + 0] = (refx + ox) * Wl - 0.5f;
        f[3 * j + 1] = (refy + oy) * Wl - 0.5f;
        f[3 * j + 2] = at[j] * inv;
    }

    // ---- bilinear sampling (validated R11/R12) ----
    float o0 = 0.f, o1 = 0.f, o2 = 0.f, o3 = 0.f;

#pragma unroll
    for (int l = 0; l < 3; ++l) {
        const int Wl = (l == 0) ? 100 : (l == 1) ? 50 : 25;
        const int Hl = Wl;
        const int HW = Wl * Hl;
        const unsigned short* vh =
            ((l == 0) ? v0 : (l == 1) ? v1 : v2) +
            ((size_t)(b * NHEAD + h) * HW) * 32;

        int   cidx[16];
        float cwt[16];
#pragma unroll
        for (int p = 0; p < 4; ++p) {
            const int j = l * 4 + p;
            const float x  = f[3 * j + 0];
            const float y  = f[3 * j + 1];
            const float aw = f[3 * j + 2];
            const float xf = floorf(x), yf = floorf(y);
            const int   x0i = (int)xf, y0i = (int)yf;
            const float wx = x - xf, wy = y - yf;
#pragma unroll
            for (int cy = 0; cy < 2; ++cy) {
#pragma unroll
                for (int cx = 0; cx < 2; ++cx) {
                    const int xi = x0i + cx, yi = y0i + cy;
                    const bool valid =
                        (xi >= 0) & (xi < Wl) & (yi >= 0) & (yi < Hl);
                    const int xc = min(max(xi, 0), Wl - 1);
                    const int yc = min(max(yi, 0), Hl - 1);
                    const float w = aw * (cx ? wx : 1.f - wx)
                                       * (cy ? wy : 1.f - wy);
                    cidx[p * 4 + cy * 2 + cx] = yc * Wl + xc;
                    cwt [p * 4 + cy * 2 + cx] = valid ? w : 0.f;
                }
            }
        }
#pragma unroll
        for (int k = 0; k < 16; ++k) {
            const ushort4 u = *(const ushort4*)(vh + (size_t)cidx[k] * 32 + co * 4);
            const float cw = cwt[k];
            o0 = fmaf(cw, bf2f(u.x), o0);
            o1 = fmaf(cw, bf2f(u.y), o1);
            o2 = fmaf(cw, bf2f(u.z), o2);
            o3 = fmaf(cw, bf2f(u.w), o3);
        }
    }

    unsigned int lo = (unsigned int)f2bf(o0) | ((unsigned int)f2bf(o1) << 16);
    unsigned int hi = (unsigned int)f2bf(o2) | ((unsigned int)f2bf(o3) << 16);
    *(uint2*)(outp + (size_t)qq * 256 + h * 32 + co * 4) = make_uint2(lo, hi);
}

// ---------------------------------------------------------------------------
// K4: output projection via bf16 MFMA (validated R7).
// ---------------------------------------------------------------------------
__global__ __launch_bounds__(256) void outproj_kernel(
    const unsigned short* __restrict__ A, const unsigned short* __restrict__ WoT,
    const float* __restrict__ bo, float* __restrict__ out)
{
    const int tid  = threadIdx.x;
    const int wave = tid >> 6;
    const int lane = tid & 63;
    const int c    = lane & 15;
    const int g    = lane >> 4;
    const int row0 = blockIdx.x * 64;
    const int n0   = wave * 64;

    f32x4 acc[4][4];
#pragma unroll
    for (int mt = 0; mt < 4; ++mt)
#pragma unroll
        for (int nt = 0; nt < 4; ++nt)
            acc[mt][nt] = (f32x4){0.f, 0.f, 0.f, 0.f};

    const unsigned short* Abase = A   + (size_t)(row0 + c) * 256 + 8 * g;
    const unsigned short* Bbase = WoT + (size_t)(n0   + c) * 256 + 8 * g;

#pragma unroll
    for (int ks = 0; ks < 8; ++ks) {
        bf16x8 a[4], bvec[4];
#pragma unroll
        for (int t = 0; t < 4; ++t) {
            a[t]    = *(const bf16x8*)(Abase + (size_t)t * 16 * 256 + ks * 32);
            bvec[t] = *(const bf16x8*)(Bbase + (size_t)t * 16 * 256 + ks * 32);
        }
#pragma unroll
        for (int mt = 0; mt < 4; ++mt)
#pragma unroll
            for (int nt = 0; nt < 4; ++nt)
                acc[mt][nt] = __builtin_amdgcn_mfma_f32_16x16x32_bf16(
                    a[mt], bvec[nt], acc[mt][nt], 0, 0, 0);
    }

#pragma unroll
    for (int nt = 0; nt < 4; ++nt) {
        const int col  = n0 + nt * 16 + c;
        const float bias = bo[col];
#pragma unroll
        for (int mt = 0; mt < 4; ++mt) {
#pragma unroll
            for (int j = 0; j < 4; ++j) {
                const int row = row0 + mt * 16 + g * 4 + j;
                out[(size_t)row * 256 + col] = acc[mt][nt][j] + bias;
            }
        }
    }
}

// ---------------------------------------------------------------------------
extern "C" void kernel_launch(void* const* d_in, const int* in_sizes, int n_in,
                              void* d_out, int out_size, void* d_ws, size_t ws_size,
                              hipStream_t stream)
{
    const float* query  = (const float*)d_in[0];
    const float* value0 = (const float*)d_in[1];
    const float* value1 = (const float*)d_in[2];
    const float* value2 = (const float*)d_in[3];
    const float* refpts = (const float*)d_in[4];
    const float* Woff   = (const float*)d_in[5];
    const float* boff   = (const float*)d_in[6];
    const float* Wattn  = (const float*)d_in[7];
    const float* battn  = (const float*)d_in[8];
    const float* Wval   = (const float*)d_in[9];
    const float* bval   = (const float*)d_in[10];
    const float* Wout   = (const float*)d_in[11];
    const float* bout   = (const float*)d_in[12];
    float* out = (float*)d_out;

    // workspace: logits 46.08 + v 26.88 + A_bf 20.48 + weights 0.68 = 94.1 MB
    float*          logits = (float*)d_ws;
    unsigned short* v0   = (unsigned short*)(logits + (size_t)NQ * 288);
    unsigned short* v1   = v0 + (size_t)BATCH * 10000 * 256;
    unsigned short* v2   = v1 + (size_t)BATCH * 2500  * 256;
    unsigned short* A_bf = v2 + (size_t)BATCH * 625   * 256;
    unsigned short* WoT  = A_bf + (size_t)NQ * 256;
    unsigned short* WTh  = WoT + (size_t)256 * 256;
    unsigned short* WTl  = WTh + (size_t)288 * 256;   // contiguous after WTh
    unsigned short* WvTh = WTl + (size_t)288 * 256;
    unsigned short* WvTl = WvTh + (size_t)256 * 256;

    wprep_kernel<<<800, 256, 0, stream>>>(Woff, Wattn, Wout, Wval,
                                          WTh, WTl, WoT, WvTh, WvTl);

    vproj_kernel<<<dim3(207, BATCH), 256, 0, stream>>>(
        value0, value1, value2, WvTh, WvTl, bval, v0, v1, v2);

    qgemm_kernel<<<NQ / 32, 256, 0, stream>>>(query, WTh, logits);

    sample_kernel<<<dim3(313, NHEAD, BATCH), 256, 0, stream>>>(
        logits, refpts, boff, battn, v0, v1, v2, A_bf);

    outproj_kernel<<<NQ / 64, 256, 0, stream>>>(A_bf, WoT, bout, out);
}

// Round 14
// 228.472 us; speedup vs baseline: 1.0821x; 1.0821x over previous
//
#include <hip/hip_runtime.h>
#include <math.h>

#define DMODEL 256
#define NHEAD 8
#define NLVL 3
#define NPTS 4
#define HDIM 32
#define QLEN 10000
#define BATCH 4
#define NQ (BATCH * QLEN)

typedef __attribute__((ext_vector_type(8))) short bf16x8;
typedef __attribute__((ext_vector_type(4))) float f32x4;

__device__ __forceinline__ float tanh_fast(float x)
{
    const float ax = fabsf(x);
    const float e  = __expf(-2.f * ax);
    const float t  = (1.f - e) / (1.f + e);
    return copysignf(t, x);
}

__device__ __forceinline__ unsigned short f2bf(float f)
{
    unsigned int u = __float_as_uint(f);
    u = (u + 0x7FFFu + ((u >> 16) & 1u)) >> 16;
    return (unsigned short)u;
}

__device__ __forceinline__ float bf2f(unsigned short s)
{
    return __uint_as_float(((unsigned int)s) << 16);
}

// ---------------------------------------------------------------------------
// K0: weight prep (once).
// ---------------------------------------------------------------------------
__global__ __launch_bounds__(256) void wprep_kernel(
    const float* __restrict__ Woff, const float* __restrict__ Wattn,
    const float* __restrict__ Wout, const float* __restrict__ Wval,
    unsigned short* __restrict__ WTh, unsigned short* __restrict__ WTl,
    unsigned short* __restrict__ WoT,
    unsigned short* __restrict__ WvTh, unsigned short* __restrict__ WvTl)
{
    const int k = threadIdx.x;
    const int n = blockIdx.x;
    if (n < 288) {
        const float w = (n < 192) ? Woff[(size_t)k * 192 + n]
                                  : Wattn[(size_t)k * 96 + (n - 192)];
        const unsigned short hi = f2bf(w);
        WTh[(size_t)n * 256 + k] = hi;
        WTl[(size_t)n * 256 + k] = f2bf(w - bf2f(hi));
    } else if (n < 544) {
        const int nn = n - 288;
        WoT[(size_t)nn * 256 + k] = f2bf(Wout[(size_t)k * 256 + nn]);
    } else {
        const int nn = n - 544;
        const float w = Wval[(size_t)k * 256 + nn];
        const unsigned short hi = f2bf(w);
        WvTh[(size_t)nn * 256 + k] = hi;
        WvTl[(size_t)nn * 256 + k] = f2bf(w - bf2f(hi));
    }
}

// ---------------------------------------------------------------------------
// K1: value projection via bf16 MFMA (validated R10/R11).  Output HEAD-MAJOR
// v[b][h][pos][32].
// ---------------------------------------------------------------------------
__global__ __launch_bounds__(256) void vproj_kernel(
    const float* __restrict__ feat0, const float* __restrict__ feat1,
    const float* __restrict__ feat2,
    const unsigned short* __restrict__ WvTh, const unsigned short* __restrict__ WvTl,
    const float* __restrict__ bv,
    unsigned short* __restrict__ v0, unsigned short* __restrict__ v1,
    unsigned short* __restrict__ v2)
{
    __shared__ short As[32 * 64 * 8];   // [kc][pos][8] = 32 KB

    const int bx = blockIdx.x;
    const int b  = blockIdx.y;

    const float* feat;
    unsigned short* vout;
    int HW, pos0;
    if (bx < 157)      { feat = feat0; vout = v0; HW = 10000; pos0 = bx * 64; }
    else if (bx < 197) { feat = feat1; vout = v1; HW = 2500;  pos0 = (bx - 157) * 64; }
    else               { feat = feat2; vout = v2; HW = 625;   pos0 = (bx - 197) * 64; }

    const int tid  = threadIdx.x;
    const int wv   = tid >> 6;
    const int lane = tid & 63;
    const int c    = lane & 15;
    const int g    = lane >> 4;

    const int sp = tid & 63;
    const int kb = (tid >> 6) * 64;
    const bool pv = (pos0 + sp) < HW;
    const float* fcol = feat + (size_t)b * DMODEL * HW + pos0 + sp;

#pragma unroll
    for (int i = 0; i < 8; ++i) {
        short h8[8];
#pragma unroll
        for (int j = 0; j < 8; ++j) {
            const int k = kb + i * 8 + j;
            const float f = pv ? fcol[(size_t)k * HW] : 0.f;
            h8[j] = (short)f2bf(f);
        }
        *(bf16x8*)&As[((size_t)(kb / 8 + i) * 64 + sp) * 8] = *(bf16x8*)h8;
    }
    __syncthreads();

    f32x4 acc[4][4];
#pragma unroll
    for (int mt = 0; mt < 4; ++mt)
#pragma unroll
        for (int nt = 0; nt < 4; ++nt)
            acc[mt][nt] = (f32x4){0.f, 0.f, 0.f, 0.f};

#pragma unroll
    for (int ks = 0; ks < 8; ++ks) {
        bf16x8 a[4];
#pragma unroll
        for (int mt = 0; mt < 4; ++mt)
            a[mt] = *(const bf16x8*)&As[((size_t)(ks * 4 + g) * 64 + mt * 16 + c) * 8];
        bf16x8 bh[4], bl[4];
#pragma unroll
        for (int nt = 0; nt < 4; ++nt) {
            const size_t off = (size_t)(wv * 64 + nt * 16 + c) * 256 + ks * 32 + 8 * g;
            bh[nt] = *(const bf16x8*)(WvTh + off);
            bl[nt] = *(const bf16x8*)(WvTl + off);
        }
#pragma unroll
        for (int mt = 0; mt < 4; ++mt)
#pragma unroll
            for (int nt = 0; nt < 4; ++nt) {
                acc[mt][nt] = __builtin_amdgcn_mfma_f32_16x16x32_bf16(
                    a[mt], bh[nt], acc[mt][nt], 0, 0, 0);
                acc[mt][nt] = __builtin_amdgcn_mfma_f32_16x16x32_bf16(
                    a[mt], bl[nt], acc[mt][nt], 0, 0, 0);
            }
    }

    unsigned short* vb = vout + (size_t)b * NHEAD * HW * 32;
#pragma unroll
    for (int nt = 0; nt < 4; ++nt) {
        const int col  = wv * 64 + nt * 16 + c;
        const int hh   = col >> 5;
        const int cc   = col & 31;
        const float bias = bv[col];
#pragma unroll
        for (int mt = 0; mt < 4; ++mt) {
#pragma unroll
            for (int j = 0; j < 4; ++j) {
                const int p = mt * 16 + g * 4 + j;
                if (pos0 + p < HW)
                    vb[((size_t)hh * HW + pos0 + p) * 32 + cc] =
                        f2bf(acc[mt][nt][j] + bias);
            }
        }
    }
}

// ---------------------------------------------------------------------------
// K2: query-side GEMM ONLY (validated R13).  32 rows/block, col-split waves,
// conflict-free subtile LDS.  Writes raw logits f32.
// ---------------------------------------------------------------------------
__global__ __launch_bounds__(256) void qgemm_kernel(
    const float* __restrict__ query,
    const unsigned short* __restrict__ WTh,
    float* __restrict__ logits)
{
    __shared__ __align__(16) short Bs[2 * 18 * 64 * 8];   // 36864 B

    const int tid  = threadIdx.x;
    const int wt   = tid >> 6;
    const int lane = tid & 63;
    const int c    = lane & 15;
    const int g    = lane >> 4;
    const int row0 = blockIdx.x * 32;

    int srco[9], dsto[9];
#pragma unroll
    for (int i = 0; i < 9; ++i) {
        const int ch  = tid + 256 * i;            // 0..2303
        const int hl  = ch >= 1152;
        const int rem = hl ? ch - 1152 : ch;
        const int col = rem >> 2;
        const int gg  = rem & 3;
        srco[i] = hl * (288 * 256) + col * 256 + gg * 8;
        dsto[i] = (hl * 1152 + (col >> 4) * 64 + gg * 16 + (col & 15)) * 8;
    }

    const float* qr[2];
#pragma unroll
    for (int t = 0; t < 2; ++t)
        qr[t] = query + (size_t)(row0 + t * 16 + c) * 256 + 8 * g;

    f32x4 acc[2][5];
#pragma unroll
    for (int t = 0; t < 2; ++t)
#pragma unroll
        for (int i = 0; i < 5; ++i) acc[t][i] = (f32x4){0.f, 0.f, 0.f, 0.f};

    for (int ks = 0; ks < 8; ++ks) {
#pragma unroll
        for (int i = 0; i < 9; ++i)
            *(bf16x8*)(Bs + dsto[i]) = *(const bf16x8*)(WTh + srco[i] + ks * 32);
        __syncthreads();

        bf16x8 a_hi[2], a_lo[2];
#pragma unroll
        for (int t = 0; t < 2; ++t) {
            const float4 q0 = *(const float4*)(qr[t] + ks * 32);
            const float4 q1 = *(const float4*)(qr[t] + ks * 32 + 4);
            const float av[8] = {q0.x, q0.y, q0.z, q0.w, q1.x, q1.y, q1.z, q1.w};
#pragma unroll
            for (int j = 0; j < 8; ++j) {
                const unsigned short hi = f2bf(av[j]);
                a_hi[t][j] = (short)hi;
                a_lo[t][j] = (short)f2bf(av[j] - bf2f(hi));
            }
        }

#pragma unroll
        for (int i = 0; i < 5; ++i) {
            const int nt = wt + 4 * i;
            if (nt < 18) {
                const bf16x8 b_hi = *(const bf16x8*)(Bs + (nt * 64 + g * 16 + c) * 8);
                const bf16x8 b_lo = *(const bf16x8*)(Bs + (1152 + nt * 64 + g * 16 + c) * 8);
#pragma unroll
                for (int t = 0; t < 2; ++t) {
                    acc[t][i] = __builtin_amdgcn_mfma_f32_16x16x32_bf16(
                        a_hi[t], b_hi, acc[t][i], 0, 0, 0);
                    acc[t][i] = __builtin_amdgcn_mfma_f32_16x16x32_bf16(
                        a_lo[t], b_hi, acc[t][i], 0, 0, 0);
                    acc[t][i] = __builtin_amdgcn_mfma_f32_16x16x32_bf16(
                        a_hi[t], b_lo, acc[t][i], 0, 0, 0);
                }
            }
        }
        __syncthreads();
    }

#pragma unroll
    for (int i = 0; i < 5; ++i) {
        const int nt = wt + 4 * i;
        if (nt < 18) {
            const int col = nt * 16 + c;
#pragma unroll
            for (int t = 0; t < 2; ++t)
#pragma unroll
                for (int j = 0; j < 4; ++j)
                    logits[(size_t)(row0 + t * 16 + 4 * g + j) * 288 + col] =
                        acc[t][i][j];
        }
    }
}

// ---------------------------------------------------------------------------
// K3: sampler with COOPERATIVE epilogue.  Block = (32 q, head h, batch b);
// 8-lane (q,h) group: lane co OWNS points {co, co+8 (co<4)} -- computes
// tanh/softmax-partial/corner data ONCE; softmax via 8-wide shfl_xor tree;
// corner idx/wt shared via ds_bpermute (LDS pipe, VALU-free).  Gather-FMA
// unchanged.
// ---------------------------------------------------------------------------
__global__ __launch_bounds__(256) void sample_kernel(
    const float* __restrict__ logits,
    const float* __restrict__ ref,
    const float* __restrict__ boff, const float* __restrict__ battn,
    const unsigned short* __restrict__ v0,
    const unsigned short* __restrict__ v1,
    const unsigned short* __restrict__ v2,
    unsigned short* __restrict__ outp)
{
    const int tid  = threadIdx.x;
    const int wv   = tid >> 6;
    const int lane = tid & 63;
    const int qd   = lane >> 3;
    const int co   = lane & 7;
    const int h    = blockIdx.y;
    const int b    = blockIdx.z;
    const int q    = blockIdx.x * 32 + wv * 8 + qd;
    if (q >= QLEN) return;               // whole 8-lane group exits together
    const int qq   = b * QLEN + q;

    const float* lgq  = logits + (size_t)qq * 288;
    const int bpbase  = (lane & 56) * 4;     // byte index of group lane 0

    // ---- distributed softmax over the 12 attn logits ----
    const float at0 = lgq[192 + h * 12 + co] + battn[h * 12 + co];
    const float at1 = (co < 4)
        ? lgq[192 + h * 12 + 8 + co] + battn[h * 12 + 8 + co] : -1e30f;
    float mx = fmaxf(at0, at1);
#pragma unroll
    for (int msk = 1; msk < 8; msk <<= 1)
        mx = fmaxf(mx, __shfl_xor(mx, msk, 8));
    const float e0 = __expf(at0 - mx);
    const float e1 = (co < 4) ? __expf(at1 - mx) : 0.f;
    float sm = e0 + e1;
#pragma unroll
    for (int msk = 1; msk < 8; msk <<= 1)
        sm += __shfl_xor(sm, msk, 8);
    const float inv = 1.f / sm;

    const float refx = ref[(size_t)qq * 2 + 0];
    const float refy = ref[(size_t)qq * 2 + 1];

    // ---- owner: corner data for points co (slot 0) and co+8 (slot 1) ----
    int   oidx[2][4];
    float owt [2][4];
#pragma unroll
    for (int s = 0; s < 2; ++s) {
        const int pt = co + 8 * s;                   // slot1 valid only co<4
        const int l  = (s == 0) ? (co >> 2) : 2;
        const int Wl = (l == 0) ? 100 : (l == 1) ? 50 : 25;
        const float aw  = (s ? e1 : e0) * inv;
        const float lgx = lgq[h * 24 + 2 * pt]     + boff[h * 24 + 2 * pt];
        const float lgy = lgq[h * 24 + 2 * pt + 1] + boff[h * 24 + 2 * pt + 1];
        const float x = (refx + 0.5f * tanh_fast(lgx)) * (float)Wl - 0.5f;
        const float y = (refy + 0.5f * tanh_fast(lgy)) * (float)Wl - 0.5f;
        const float xf = floorf(x), yf = floorf(y);
        const int   x0i = (int)xf, y0i = (int)yf;
        const float wx = x - xf, wy = y - yf;
#pragma unroll
        for (int cy = 0; cy < 2; ++cy) {
#pragma unroll
            for (int cx = 0; cx < 2; ++cx) {
                const int xi = x0i + cx, yi = y0i + cy;
                const bool valid = (xi >= 0) & (xi < Wl) & (yi >= 0) & (yi < Wl);
                const int xc = min(max(xi, 0), Wl - 1);
                const int yc = min(max(yi, 0), Wl - 1);
                oidx[s][cy * 2 + cx] = yc * Wl + xc;
                owt [s][cy * 2 + cx] = valid
                    ? aw * (cx ? wx : 1.f - wx) * (cy ? wy : 1.f - wy) : 0.f;
            }
        }
    }

    // ---- gather: per level, broadcast owners' corner data via bpermute ----
    float o0 = 0.f, o1 = 0.f, o2 = 0.f, o3 = 0.f;

#pragma unroll
    for (int l = 0; l < 3; ++l) {
        const int Wl = (l == 0) ? 100 : (l == 1) ? 50 : 25;
        const int HW = Wl * Wl;
        const unsigned short* vh =
            ((l == 0) ? v0 : (l == 1) ? v1 : v2) +
            ((size_t)(b * NHEAD + h) * HW) * 32;

#pragma unroll
        for (int p = 0; p < 4; ++p) {
            const int src  = (l == 2) ? p : l * 4 + p;
            const int slot = (l == 2) ? 1 : 0;
#pragma unroll
            for (int k = 0; k < 4; ++k) {
                const int ci = __builtin_amdgcn_ds_bpermute(
                    bpbase + 4 * src, oidx[slot][k]);
                const int cwbits = __builtin_amdgcn_ds_bpermute(
                    bpbase + 4 * src, __float_as_int(owt[slot][k]));
                const float cw = __int_as_float(cwbits);
                const ushort4 u = *(const ushort4*)(vh + (size_t)ci * 32 + co * 4);
                o0 = fmaf(cw, bf2f(u.x), o0);
                o1 = fmaf(cw, bf2f(u.y), o1);
                o2 = fmaf(cw, bf2f(u.z), o2);
                o3 = fmaf(cw, bf2f(u.w), o3);
            }
        }
    }

    unsigned int lo = (unsigned int)f2bf(o0) | ((unsigned int)f2bf(o1) << 16);
    unsigned int hi = (unsigned int)f2bf(o2) | ((unsigned int)f2bf(o3) << 16);
    *(uint2*)(outp + (size_t)qq * 256 + h * 32 + co * 4) = make_uint2(lo, hi);
}

// ---------------------------------------------------------------------------
// K4: output projection via bf16 MFMA (validated R7).
// ---------------------------------------------------------------------------
__global__ __launch_bounds__(256) void outproj_kernel(
    const unsigned short* __restrict__ A, const unsigned short* __restrict__ WoT,
    const float* __restrict__ bo, float* __restrict__ out)
{
    const int tid  = threadIdx.x;
    const int wave = tid >> 6;
    const int lane = tid & 63;
    const int c    = lane & 15;
    const int g    = lane >> 4;
    const int row0 = blockIdx.x * 64;
    const int n0   = wave * 64;

    f32x4 acc[4][4];
#pragma unroll
    for (int mt = 0; mt < 4; ++mt)
#pragma unroll
        for (int nt = 0; nt < 4; ++nt)
            acc[mt][nt] = (f32x4){0.f, 0.f, 0.f, 0.f};

    const unsigned short* Abase = A   + (size_t)(row0 + c) * 256 + 8 * g;
    const unsigned short* Bbase = WoT + (size_t)(n0   + c) * 256 + 8 * g;

#pragma unroll
    for (int ks = 0; ks < 8; ++ks) {
        bf16x8 a[4], bvec[4];
#pragma unroll
        for (int t = 0; t < 4; ++t) {
            a[t]    = *(const bf16x8*)(Abase + (size_t)t * 16 * 256 + ks * 32);
            bvec[t] = *(const bf16x8*)(Bbase + (size_t)t * 16 * 256 + ks * 32);
        }
#pragma unroll
        for (int mt = 0; mt < 4; ++mt)
#pragma unroll
            for (int nt = 0; nt < 4; ++nt)
                acc[mt][nt] = __builtin_amdgcn_mfma_f32_16x16x32_bf16(
                    a[mt], bvec[nt], acc[mt][nt], 0, 0, 0);
    }

#pragma unroll
    for (int nt = 0; nt < 4; ++nt) {
        const int col  = n0 + nt * 16 + c;
        const float bias = bo[col];
#pragma unroll
        for (int mt = 0; mt < 4; ++mt) {
#pragma unroll
            for (int j = 0; j < 4; ++j) {
                const int row = row0 + mt * 16 + g * 4 + j;
                out[(size_t)row * 256 + col] = acc[mt][nt][j] + bias;
            }
        }
    }
}

// ---------------------------------------------------------------------------
extern "C" void kernel_launch(void* const* d_in, const int* in_sizes, int n_in,
                              void* d_out, int out_size, void* d_ws, size_t ws_size,
                              hipStream_t stream)
{
    const float* query  = (const float*)d_in[0];
    const float* value0 = (const float*)d_in[1];
    const float* value1 = (const float*)d_in[2];
    const float* value2 = (const float*)d_in[3];
    const float* refpts = (const float*)d_in[4];
    const float* Woff   = (const float*)d_in[5];
    const float* boff   = (const float*)d_in[6];
    const float* Wattn  = (const float*)d_in[7];
    const float* battn  = (const float*)d_in[8];
    const float* Wval   = (const float*)d_in[9];
    const float* bval   = (const float*)d_in[10];
    const float* Wout   = (const float*)d_in[11];
    const float* bout   = (const float*)d_in[12];
    float* out = (float*)d_out;

    float*          logits = (float*)d_ws;
    unsigned short* v0   = (unsigned short*)(logits + (size_t)NQ * 288);
    unsigned short* v1   = v0 + (size_t)BATCH * 10000 * 256;
    unsigned short* v2   = v1 + (size_t)BATCH * 2500  * 256;
    unsigned short* A_bf = v2 + (size_t)BATCH * 625   * 256;
    unsigned short* WoT  = A_bf + (size_t)NQ * 256;
    unsigned short* WTh  = WoT + (size_t)256 * 256;
    unsigned short* WTl  = WTh + (size_t)288 * 256;   // contiguous after WTh
    unsigned short* WvTh = WTl + (size_t)288 * 256;
    unsigned short* WvTl = WvTh + (size_t)256 * 256;

    wprep_kernel<<<800, 256, 0, stream>>>(Woff, Wattn, Wout, Wval,
                                          WTh, WTl, WoT, WvTh, WvTl);

    vproj_kernel<<<dim3(207, BATCH), 256, 0, stream>>>(
        value0, value1, value2, WvTh, WvTl, bval, v0, v1, v2);

    qgemm_kernel<<<NQ / 32, 256, 0, stream>>>(query, WTh, logits);

    sample_kernel<<<dim3(313, NHEAD, BATCH), 256, 0, stream>>>(
        logits, refpts, boff, battn, v0, v1, v2, A_bf);

    outproj_kernel<<<NQ / 64, 256, 0, stream>>>(A_bf, WoT, bout, out);
}

// Round 15
// 223.022 us; speedup vs baseline: 1.1085x; 1.0244x over previous
//
#include <hip/hip_runtime.h>
#include <math.h>

#define DMODEL 256
#define NHEAD 8
#define NLVL 3
#define NPTS 4
#define HDIM 32
#define QLEN 10000
#define BATCH 4
#define NQ (BATCH * QLEN)

typedef __attribute__((ext_vector_type(8))) short bf16x8;
typedef __attribute__((ext_vector_type(4))) float f32x4;

__device__ __forceinline__ float tanh_fast(float x)
{
    const float ax = fabsf(x);
    const float e  = __expf(-2.f * ax);
    const float t  = (1.f - e) / (1.f + e);
    return copysignf(t, x);
}

__device__ __forceinline__ unsigned short f2bf(float f)
{
    unsigned int u = __float_as_uint(f);
    u = (u + 0x7FFFu + ((u >> 16) & 1u)) >> 16;
    return (unsigned short)u;
}

__device__ __forceinline__ float bf2f(unsigned short s)
{
    return __uint_as_float(((unsigned int)s) << 16);
}

// ---------------------------------------------------------------------------
// K0: weight prep (once).
// ---------------------------------------------------------------------------
__global__ __launch_bounds__(256) void wprep_kernel(
    const float* __restrict__ Woff, const float* __restrict__ Wattn,
    const float* __restrict__ Wout, const float* __restrict__ Wval,
    unsigned short* __restrict__ WTh, unsigned short* __restrict__ WTl,
    unsigned short* __restrict__ WoT,
    unsigned short* __restrict__ WvTh, unsigned short* __restrict__ WvTl)
{
    const int k = threadIdx.x;
    const int n = blockIdx.x;
    if (n < 288) {
        const float w = (n < 192) ? Woff[(size_t)k * 192 + n]
                                  : Wattn[(size_t)k * 96 + (n - 192)];
        const unsigned short hi = f2bf(w);
        WTh[(size_t)n * 256 + k] = hi;
        WTl[(size_t)n * 256 + k] = f2bf(w - bf2f(hi));
    } else if (n < 544) {
        const int nn = n - 288;
        WoT[(size_t)nn * 256 + k] = f2bf(Wout[(size_t)k * 256 + nn]);
    } else {
        const int nn = n - 544;
        const float w = Wval[(size_t)k * 256 + nn];
        const unsigned short hi = f2bf(w);
        WvTh[(size_t)nn * 256 + k] = hi;
        WvTl[(size_t)nn * 256 + k] = f2bf(w - bf2f(hi));
    }
}

// ---------------------------------------------------------------------------
// K1: value projection via bf16 MFMA (validated R10/R11).  Output HEAD-MAJOR
// v[b][h][pos][32].
// ---------------------------------------------------------------------------
__global__ __launch_bounds__(256) void vproj_kernel(
    const float* __restrict__ feat0, const float* __restrict__ feat1,
    const float* __restrict__ feat2,
    const unsigned short* __restrict__ WvTh, const unsigned short* __restrict__ WvTl,
    const float* __restrict__ bv,
    unsigned short* __restrict__ v0, unsigned short* __restrict__ v1,
    unsigned short* __restrict__ v2)
{
    __shared__ short As[32 * 64 * 8];   // [kc][pos][8] = 32 KB

    const int bx = blockIdx.x;
    const int b  = blockIdx.y;

    const float* feat;
    unsigned short* vout;
    int HW, pos0;
    if (bx < 157)      { feat = feat0; vout = v0; HW = 10000; pos0 = bx * 64; }
    else if (bx < 197) { feat = feat1; vout = v1; HW = 2500;  pos0 = (bx - 157) * 64; }
    else               { feat = feat2; vout = v2; HW = 625;   pos0 = (bx - 197) * 64; }

    const int tid  = threadIdx.x;
    const int wv   = tid >> 6;
    const int lane = tid & 63;
    const int c    = lane & 15;
    const int g    = lane >> 4;

    const int sp = tid & 63;
    const int kb = (tid >> 6) * 64;
    const bool pv = (pos0 + sp) < HW;
    const float* fcol = feat + (size_t)b * DMODEL * HW + pos0 + sp;

#pragma unroll
    for (int i = 0; i < 8; ++i) {
        short h8[8];
#pragma unroll
        for (int j = 0; j < 8; ++j) {
            const int k = kb + i * 8 + j;
            const float f = pv ? fcol[(size_t)k * HW] : 0.f;
            h8[j] = (short)f2bf(f);
        }
        *(bf16x8*)&As[((size_t)(kb / 8 + i) * 64 + sp) * 8] = *(bf16x8*)h8;
    }
    __syncthreads();

    f32x4 acc[4][4];
#pragma unroll
    for (int mt = 0; mt < 4; ++mt)
#pragma unroll
        for (int nt = 0; nt < 4; ++nt)
            acc[mt][nt] = (f32x4){0.f, 0.f, 0.f, 0.f};

#pragma unroll
    for (int ks = 0; ks < 8; ++ks) {
        bf16x8 a[4];
#pragma unroll
        for (int mt = 0; mt < 4; ++mt)
            a[mt] = *(const bf16x8*)&As[((size_t)(ks * 4 + g) * 64 + mt * 16 + c) * 8];
        bf16x8 bh[4], bl[4];
#pragma unroll
        for (int nt = 0; nt < 4; ++nt) {
            const size_t off = (size_t)(wv * 64 + nt * 16 + c) * 256 + ks * 32 + 8 * g;
            bh[nt] = *(const bf16x8*)(WvTh + off);
            bl[nt] = *(const bf16x8*)(WvTl + off);
        }
#pragma unroll
        for (int mt = 0; mt < 4; ++mt)
#pragma unroll
            for (int nt = 0; nt < 4; ++nt) {
                acc[mt][nt] = __builtin_amdgcn_mfma_f32_16x16x32_bf16(
                    a[mt], bh[nt], acc[mt][nt], 0, 0, 0);
                acc[mt][nt] = __builtin_amdgcn_mfma_f32_16x16x32_bf16(
                    a[mt], bl[nt], acc[mt][nt], 0, 0, 0);
            }
    }

    unsigned short* vb = vout + (size_t)b * NHEAD * HW * 32;
#pragma unroll
    for (int nt = 0; nt < 4; ++nt) {
        const int col  = wv * 64 + nt * 16 + c;
        const int hh   = col >> 5;
        const int cc   = col & 31;
        const float bias = bv[col];
#pragma unroll
        for (int mt = 0; mt < 4; ++mt) {
#pragma unroll
            for (int j = 0; j < 4; ++j) {
                const int p = mt * 16 + g * 4 + j;
                if (pos0 + p < HW)
                    vb[((size_t)hh * HW + pos0 + p) * 32 + cc] =
                        f2bf(acc[mt][nt][j] + bias);
            }
        }
    }
}

// ---------------------------------------------------------------------------
// K2: query-side GEMM ONLY (validated R13).  32 rows/block, col-split waves,
// conflict-free subtile LDS.  Writes raw logits f32.
// ---------------------------------------------------------------------------
__global__ __launch_bounds__(256) void qgemm_kernel(
    const float* __restrict__ query,
    const unsigned short* __restrict__ WTh,
    float* __restrict__ logits)
{
    __shared__ __align__(16) short Bs[2 * 18 * 64 * 8];   // 36864 B

    const int tid  = threadIdx.x;
    const int wt   = tid >> 6;
    const int lane = tid & 63;
    const int c    = lane & 15;
    const int g    = lane >> 4;
    const int row0 = blockIdx.x * 32;

    int srco[9], dsto[9];
#pragma unroll
    for (int i = 0; i < 9; ++i) {
        const int ch  = tid + 256 * i;            // 0..2303
        const int hl  = ch >= 1152;
        const int rem = hl ? ch - 1152 : ch;
        const int col = rem >> 2;
        const int gg  = rem & 3;
        srco[i] = hl * (288 * 256) + col * 256 + gg * 8;
        dsto[i] = (hl * 1152 + (col >> 4) * 64 + gg * 16 + (col & 15)) * 8;
    }

    const float* qr[2];
#pragma unroll
    for (int t = 0; t < 2; ++t)
        qr[t] = query + (size_t)(row0 + t * 16 + c) * 256 + 8 * g;

    f32x4 acc[2][5];
#pragma unroll
    for (int t = 0; t < 2; ++t)
#pragma unroll
        for (int i = 0; i < 5; ++i) acc[t][i] = (f32x4){0.f, 0.f, 0.f, 0.f};

    for (int ks = 0; ks < 8; ++ks) {
#pragma unroll
        for (int i = 0; i < 9; ++i)
            *(bf16x8*)(Bs + dsto[i]) = *(const bf16x8*)(WTh + srco[i] + ks * 32);
        __syncthreads();

        bf16x8 a_hi[2], a_lo[2];
#pragma unroll
        for (int t = 0; t < 2; ++t) {
            const float4 q0 = *(const float4*)(qr[t] + ks * 32);
            const float4 q1 = *(const float4*)(qr[t] + ks * 32 + 4);
            const float av[8] = {q0.x, q0.y, q0.z, q0.w, q1.x, q1.y, q1.z, q1.w};
#pragma unroll
            for (int j = 0; j < 8; ++j) {
                const unsigned short hi = f2bf(av[j]);
                a_hi[t][j] = (short)hi;
                a_lo[t][j] = (short)f2bf(av[j] - bf2f(hi));
            }
        }

#pragma unroll
        for (int i = 0; i < 5; ++i) {
            const int nt = wt + 4 * i;
            if (nt < 18) {
                const bf16x8 b_hi = *(const bf16x8*)(Bs + (nt * 64 + g * 16 + c) * 8);
                const bf16x8 b_lo = *(const bf16x8*)(Bs + (1152 + nt * 64 + g * 16 + c) * 8);
#pragma unroll
                for (int t = 0; t < 2; ++t) {
                    acc[t][i] = __builtin_amdgcn_mfma_f32_16x16x32_bf16(
                        a_hi[t], b_hi, acc[t][i], 0, 0, 0);
                    acc[t][i] = __builtin_amdgcn_mfma_f32_16x16x32_bf16(
                        a_lo[t], b_hi, acc[t][i], 0, 0, 0);
                    acc[t][i] = __builtin_amdgcn_mfma_f32_16x16x32_bf16(
                        a_hi[t], b_lo, acc[t][i], 0, 0, 0);
                }
            }
        }
        __syncthreads();
    }

#pragma unroll
    for (int i = 0; i < 5; ++i) {
        const int nt = wt + 4 * i;
        if (nt < 18) {
            const int col = nt * 16 + c;
#pragma unroll
            for (int t = 0; t < 2; ++t)
#pragma unroll
                for (int j = 0; j < 4; ++j)
                    logits[(size_t)(row0 + t * 16 + 4 * g + j) * 288 + col] =
                        acc[t][i][j];
        }
    }
}

// ---------------------------------------------------------------------------
// K3: sampler, cooperative epilogue (validated R14) + XCD-AWARE 1D GRID.
// id = h + 8*(b*313 + n): all 1252 blocks of head h share id%8 -> same XCD
// under round-robin dispatch; per-XCD v working set = 4 batches x 840 KB
// = 3.36 MB (fits 4 MB L2).
// ---------------------------------------------------------------------------
__global__ __launch_bounds__(256) void sample_kernel(
    const float* __restrict__ logits,
    const float* __restrict__ ref,
    const float* __restrict__ boff, const float* __restrict__ battn,
    const unsigned short* __restrict__ v0,
    const unsigned short* __restrict__ v1,
    const unsigned short* __restrict__ v2,
    unsigned short* __restrict__ outp)
{
    const int tid  = threadIdx.x;
    const int wv   = tid >> 6;
    const int lane = tid & 63;
    const int qd   = lane >> 3;
    const int co   = lane & 7;

    const int id = blockIdx.x;           // 0..10015
    const int h  = id & 7;               // XCD key
    const int m  = id >> 3;              // 0..1251
    const int b  = m / 313;
    const int n  = m - b * 313;
    const int q  = n * 32 + wv * 8 + qd;
    if (q >= QLEN) return;               // whole 8-lane group exits together
    const int qq = b * QLEN + q;

    const float* lgq  = logits + (size_t)qq * 288;
    const int bpbase  = (lane & 56) * 4;     // byte index of group lane 0

    // ---- distributed softmax over the 12 attn logits ----
    const float at0 = lgq[192 + h * 12 + co] + battn[h * 12 + co];
    const float at1 = (co < 4)
        ? lgq[192 + h * 12 + 8 + co] + battn[h * 12 + 8 + co] : -1e30f;
    float mx = fmaxf(at0, at1);
#pragma unroll
    for (int msk = 1; msk < 8; msk <<= 1)
        mx = fmaxf(mx, __shfl_xor(mx, msk, 8));
    const float e0 = __expf(at0 - mx);
    const float e1 = (co < 4) ? __expf(at1 - mx) : 0.f;
    float sm = e0 + e1;
#pragma unroll
    for (int msk = 1; msk < 8; msk <<= 1)
        sm += __shfl_xor(sm, msk, 8);
    const float inv = 1.f / sm;

    const float refx = ref[(size_t)qq * 2 + 0];
    const float refy = ref[(size_t)qq * 2 + 1];

    // ---- owner: corner data for points co (slot 0) and co+8 (slot 1) ----
    int   oidx[2][4];
    float owt [2][4];
#pragma unroll
    for (int s = 0; s < 2; ++s) {
        const int pt = co + 8 * s;                   // slot1 valid only co<4
        const int l  = (s == 0) ? (co >> 2) : 2;
        const int Wl = (l == 0) ? 100 : (l == 1) ? 50 : 25;
        const float aw  = (s ? e1 : e0) * inv;
        const float lgx = lgq[h * 24 + 2 * pt]     + boff[h * 24 + 2 * pt];
        const float lgy = lgq[h * 24 + 2 * pt + 1] + boff[h * 24 + 2 * pt + 1];
        const float x = (refx + 0.5f * tanh_fast(lgx)) * (float)Wl - 0.5f;
        const float y = (refy + 0.5f * tanh_fast(lgy)) * (float)Wl - 0.5f;
        const float xf = floorf(x), yf = floorf(y);
        const int   x0i = (int)xf, y0i = (int)yf;
        const float wx = x - xf, wy = y - yf;
#pragma unroll
        for (int cy = 0; cy < 2; ++cy) {
#pragma unroll
            for (int cx = 0; cx < 2; ++cx) {
                const int xi = x0i + cx, yi = y0i + cy;
                const bool valid = (xi >= 0) & (xi < Wl) & (yi >= 0) & (yi < Wl);
                const int xc = min(max(xi, 0), Wl - 1);
                const int yc = min(max(yi, 0), Wl - 1);
                oidx[s][cy * 2 + cx] = yc * Wl + xc;
                owt [s][cy * 2 + cx] = valid
                    ? aw * (cx ? wx : 1.f - wx) * (cy ? wy : 1.f - wy) : 0.f;
            }
        }
    }

    // ---- gather: per level, broadcast owners' corner data via bpermute ----
    float o0 = 0.f, o1 = 0.f, o2 = 0.f, o3 = 0.f;

#pragma unroll
    for (int l = 0; l < 3; ++l) {
        const int Wl = (l == 0) ? 100 : (l == 1) ? 50 : 25;
        const int HW = Wl * Wl;
        const unsigned short* vh =
            ((l == 0) ? v0 : (l == 1) ? v1 : v2) +
            ((size_t)(b * NHEAD + h) * HW) * 32;

#pragma unroll
        for (int p = 0; p < 4; ++p) {
            const int src  = (l == 2) ? p : l * 4 + p;
            const int slot = (l == 2) ? 1 : 0;
#pragma unroll
            for (int k = 0; k < 4; ++k) {
                const int ci = __builtin_amdgcn_ds_bpermute(
                    bpbase + 4 * src, oidx[slot][k]);
                const int cwbits = __builtin_amdgcn_ds_bpermute(
                    bpbase + 4 * src, __float_as_int(owt[slot][k]));
                const float cw = __int_as_float(cwbits);
                const ushort4 u = *(const ushort4*)(vh + (size_t)ci * 32 + co * 4);
                o0 = fmaf(cw, bf2f(u.x), o0);
                o1 = fmaf(cw, bf2f(u.y), o1);
                o2 = fmaf(cw, bf2f(u.z), o2);
                o3 = fmaf(cw, bf2f(u.w), o3);
            }
        }
    }

    unsigned int lo = (unsigned int)f2bf(o0) | ((unsigned int)f2bf(o1) << 16);
    unsigned int hi = (unsigned int)f2bf(o2) | ((unsigned int)f2bf(o3) << 16);
    *(uint2*)(outp + (size_t)qq * 256 + h * 32 + co * 4) = make_uint2(lo, hi);
}

// ---------------------------------------------------------------------------
// K4: output projection via bf16 MFMA (validated R7).
// ---------------------------------------------------------------------------
__global__ __launch_bounds__(256) void outproj_kernel(
    const unsigned short* __restrict__ A, const unsigned short* __restrict__ WoT,
    const float* __restrict__ bo, float* __restrict__ out)
{
    const int tid  = threadIdx.x;
    const int wave = tid >> 6;
    const int lane = tid & 63;
    const int c    = lane & 15;
    const int g    = lane >> 4;
    const int row0 = blockIdx.x * 64;
    const int n0   = wave * 64;

    f32x4 acc[4][4];
#pragma unroll
    for (int mt = 0; mt < 4; ++mt)
#pragma unroll
        for (int nt = 0; nt < 4; ++nt)
            acc[mt][nt] = (f32x4){0.f, 0.f, 0.f, 0.f};

    const unsigned short* Abase = A   + (size_t)(row0 + c) * 256 + 8 * g;
    const unsigned short* Bbase = WoT + (size_t)(n0   + c) * 256 + 8 * g;

#pragma unroll
    for (int ks = 0; ks < 8; ++ks) {
        bf16x8 a[4], bvec[4];
#pragma unroll
        for (int t = 0; t < 4; ++t) {
            a[t]    = *(const bf16x8*)(Abase + (size_t)t * 16 * 256 + ks * 32);
            bvec[t] = *(const bf16x8*)(Bbase + (size_t)t * 16 * 256 + ks * 32);
        }
#pragma unroll
        for (int mt = 0; mt < 4; ++mt)
#pragma unroll
            for (int nt = 0; nt < 4; ++nt)
                acc[mt][nt] = __builtin_amdgcn_mfma_f32_16x16x32_bf16(
                    a[mt], bvec[nt], acc[mt][nt], 0, 0, 0);
    }

#pragma unroll
    for (int nt = 0; nt < 4; ++nt) {
        const int col  = n0 + nt * 16 + c;
        const float bias = bo[col];
#pragma unroll
        for (int mt = 0; mt < 4; ++mt) {
#pragma unroll
            for (int j = 0; j < 4; ++j) {
                const int row = row0 + mt * 16 + g * 4 + j;
                out[(size_t)row * 256 + col] = acc[mt][nt][j] + bias;
            }
        }
    }
}

// ---------------------------------------------------------------------------
extern "C" void kernel_launch(void* const* d_in, const int* in_sizes, int n_in,
                              void* d_out, int out_size, void* d_ws, size_t ws_size,
                              hipStream_t stream)
{
    const float* query  = (const float*)d_in[0];
    const float* value0 = (const float*)d_in[1];
    const float* value1 = (const float*)d_in[2];
    const float* value2 = (const float*)d_in[3];
    const float* refpts = (const float*)d_in[4];
    const float* Woff   = (const float*)d_in[5];
    const float* boff   = (const float*)d_in[6];
    const float* Wattn  = (const float*)d_in[7];
    const float* battn  = (const float*)d_in[8];
    const float* Wval   = (const float*)d_in[9];
    const float* bval   = (const float*)d_in[10];
    const float* Wout   = (const float*)d_in[11];
    const float* bout   = (const float*)d_in[12];
    float* out = (float*)d_out;

    float*          logits = (float*)d_ws;
    unsigned short* v0   = (unsigned short*)(logits + (size_t)NQ * 288);
    unsigned short* v1   = v0 + (size_t)BATCH * 10000 * 256;
    unsigned short* v2   = v1 + (size_t)BATCH * 2500  * 256;
    unsigned short* A_bf = v2 + (size_t)BATCH * 625   * 256;
    unsigned short* WoT  = A_bf + (size_t)NQ * 256;
    unsigned short* WTh  = WoT + (size_t)256 * 256;
    unsigned short* WTl  = WTh + (size_t)288 * 256;   // contiguous after WTh
    unsigned short* WvTh = WTl + (size_t)288 * 256;
    unsigned short* WvTl = WvTh + (size_t)256 * 256;

    wprep_kernel<<<800, 256, 0, stream>>>(Woff, Wattn, Wout, Wval,
                                          WTh, WTl, WoT, WvTh, WvTl);

    vproj_kernel<<<dim3(207, BATCH), 256, 0, stream>>>(
        value0, value1, value2, WvTh, WvTl, bval, v0, v1, v2);

    qgemm_kernel<<<NQ / 32, 256, 0, stream>>>(query, WTh, logits);

    sample_kernel<<<8 * 313 * BATCH, 256, 0, stream>>>(
        logits, refpts, boff, battn, v0, v1, v2, A_bf);

    outproj_kernel<<<NQ / 64, 256, 0, stream>>>(A_bf, WoT, bout, out);
}

// Round 16
// 220.508 us; speedup vs baseline: 1.1211x; 1.0114x over previous
//
#include <hip/hip_runtime.h>
#include <math.h>

#define DMODEL 256
#define NHEAD 8
#define NLVL 3
#define NPTS 4
#define HDIM 32
#define QLEN 10000
#define BATCH 4
#define NQ (BATCH * QLEN)

typedef __attribute__((ext_vector_type(8))) short bf16x8;
typedef __attribute__((ext_vector_type(4))) float f32x4;

__device__ __forceinline__ float tanh_fast(float x)
{
    const float ax = fabsf(x);
    const float e  = __expf(-2.f * ax);
    const float t  = (1.f - e) / (1.f + e);
    return copysignf(t, x);
}

__device__ __forceinline__ unsigned short f2bf(float f)
{
    unsigned int u = __float_as_uint(f);
    u = (u + 0x7FFFu + ((u >> 16) & 1u)) >> 16;
    return (unsigned short)u;
}

__device__ __forceinline__ float bf2f(unsigned short s)
{
    return __uint_as_float(((unsigned int)s) << 16);
}

// ---------------------------------------------------------------------------
// K0: weight prep (once).
// ---------------------------------------------------------------------------
__global__ __launch_bounds__(256) void wprep_kernel(
    const float* __restrict__ Woff, const float* __restrict__ Wattn,
    const float* __restrict__ Wout, const float* __restrict__ Wval,
    unsigned short* __restrict__ WTh, unsigned short* __restrict__ WTl,
    unsigned short* __restrict__ WoT,
    unsigned short* __restrict__ WvTh, unsigned short* __restrict__ WvTl)
{
    const int k = threadIdx.x;
    const int n = blockIdx.x;
    if (n < 288) {
        const float w = (n < 192) ? Woff[(size_t)k * 192 + n]
                                  : Wattn[(size_t)k * 96 + (n - 192)];
        const unsigned short hi = f2bf(w);
        WTh[(size_t)n * 256 + k] = hi;
        WTl[(size_t)n * 256 + k] = f2bf(w - bf2f(hi));
    } else if (n < 544) {
        const int nn = n - 288;
        WoT[(size_t)nn * 256 + k] = f2bf(Wout[(size_t)k * 256 + nn]);
    } else {
        const int nn = n - 544;
        const float w = Wval[(size_t)k * 256 + nn];
        const unsigned short hi = f2bf(w);
        WvTh[(size_t)nn * 256 + k] = hi;
        WvTl[(size_t)nn * 256 + k] = f2bf(w - bf2f(hi));
    }
}

// ---------------------------------------------------------------------------
// vproj body (validated R10/R11): value projection via bf16 MFMA, output
// HEAD-MAJOR v[b][h][pos][32].
// ---------------------------------------------------------------------------
__device__ __forceinline__ void vproj_body(
    const float* __restrict__ feat0, const float* __restrict__ feat1,
    const float* __restrict__ feat2,
    const unsigned short* __restrict__ WvTh, const unsigned short* __restrict__ WvTl,
    const float* __restrict__ bv,
    unsigned short* __restrict__ v0, unsigned short* __restrict__ v1,
    unsigned short* __restrict__ v2,
    int vb, short* As)
{
    const int bx = vb % 207;
    const int b  = vb / 207;

    const float* feat;
    unsigned short* vout;
    int HW, pos0;
    if (bx < 157)      { feat = feat0; vout = v0; HW = 10000; pos0 = bx * 64; }
    else if (bx < 197) { feat = feat1; vout = v1; HW = 2500;  pos0 = (bx - 157) * 64; }
    else               { feat = feat2; vout = v2; HW = 625;   pos0 = (bx - 197) * 64; }

    const int tid  = threadIdx.x;
    const int wv   = tid >> 6;
    const int lane = tid & 63;
    const int c    = lane & 15;
    const int g    = lane >> 4;

    const int sp = tid & 63;
    const int kb = (tid >> 6) * 64;
    const bool pv = (pos0 + sp) < HW;
    const float* fcol = feat + (size_t)b * DMODEL * HW + pos0 + sp;

#pragma unroll
    for (int i = 0; i < 8; ++i) {
        short h8[8];
#pragma unroll
        for (int j = 0; j < 8; ++j) {
            const int k = kb + i * 8 + j;
            const float f = pv ? fcol[(size_t)k * HW] : 0.f;
            h8[j] = (short)f2bf(f);
        }
        *(bf16x8*)&As[((size_t)(kb / 8 + i) * 64 + sp) * 8] = *(bf16x8*)h8;
    }
    __syncthreads();

    f32x4 acc[4][4];
#pragma unroll
    for (int mt = 0; mt < 4; ++mt)
#pragma unroll
        for (int nt = 0; nt < 4; ++nt)
            acc[mt][nt] = (f32x4){0.f, 0.f, 0.f, 0.f};

#pragma unroll
    for (int ks = 0; ks < 8; ++ks) {
        bf16x8 a[4];
#pragma unroll
        for (int mt = 0; mt < 4; ++mt)
            a[mt] = *(const bf16x8*)&As[((size_t)(ks * 4 + g) * 64 + mt * 16 + c) * 8];
        bf16x8 bh[4], bl[4];
#pragma unroll
        for (int nt = 0; nt < 4; ++nt) {
            const size_t off = (size_t)(wv * 64 + nt * 16 + c) * 256 + ks * 32 + 8 * g;
            bh[nt] = *(const bf16x8*)(WvTh + off);
            bl[nt] = *(const bf16x8*)(WvTl + off);
        }
#pragma unroll
        for (int mt = 0; mt < 4; ++mt)
#pragma unroll
            for (int nt = 0; nt < 4; ++nt) {
                acc[mt][nt] = __builtin_amdgcn_mfma_f32_16x16x32_bf16(
                    a[mt], bh[nt], acc[mt][nt], 0, 0, 0);
                acc[mt][nt] = __builtin_amdgcn_mfma_f32_16x16x32_bf16(
                    a[mt], bl[nt], acc[mt][nt], 0, 0, 0);
            }
    }

    unsigned short* vbp = vout + (size_t)b * NHEAD * HW * 32;
#pragma unroll
    for (int nt = 0; nt < 4; ++nt) {
        const int col  = wv * 64 + nt * 16 + c;
        const int hh   = col >> 5;
        const int cc   = col & 31;
        const float bias = bv[col];
#pragma unroll
        for (int mt = 0; mt < 4; ++mt) {
#pragma unroll
            for (int j = 0; j < 4; ++j) {
                const int p = mt * 16 + g * 4 + j;
                if (pos0 + p < HW)
                    vbp[((size_t)hh * HW + pos0 + p) * 32 + cc] =
                        f2bf(acc[mt][nt][j] + bias);
            }
        }
    }
}

// ---------------------------------------------------------------------------
// qgemm body (validated R13): query GEMM, col-split waves, conflict-free
// subtile LDS, writes raw logits f32.
// ---------------------------------------------------------------------------
__device__ __forceinline__ void qgemm_body(
    const float* __restrict__ query,
    const unsigned short* __restrict__ WTh,
    float* __restrict__ logits,
    int qb, short* Bs)
{
    const int tid  = threadIdx.x;
    const int wt   = tid >> 6;
    const int lane = tid & 63;
    const int c    = lane & 15;
    const int g    = lane >> 4;
    const int row0 = qb * 32;

    int srco[9], dsto[9];
#pragma unroll
    for (int i = 0; i < 9; ++i) {
        const int ch  = tid + 256 * i;            // 0..2303
        const int hl  = ch >= 1152;
        const int rem = hl ? ch - 1152 : ch;
        const int col = rem >> 2;
        const int gg  = rem & 3;
        srco[i] = hl * (288 * 256) + col * 256 + gg * 8;
        dsto[i] = (hl * 1152 + (col >> 4) * 64 + gg * 16 + (col & 15)) * 8;
    }

    const float* qr[2];
#pragma unroll
    for (int t = 0; t < 2; ++t)
        qr[t] = query + (size_t)(row0 + t * 16 + c) * 256 + 8 * g;

    f32x4 acc[2][5];
#pragma unroll
    for (int t = 0; t < 2; ++t)
#pragma unroll
        for (int i = 0; i < 5; ++i) acc[t][i] = (f32x4){0.f, 0.f, 0.f, 0.f};

    for (int ks = 0; ks < 8; ++ks) {
#pragma unroll
        for (int i = 0; i < 9; ++i)
            *(bf16x8*)(Bs + dsto[i]) = *(const bf16x8*)(WTh + srco[i] + ks * 32);
        __syncthreads();

        bf16x8 a_hi[2], a_lo[2];
#pragma unroll
        for (int t = 0; t < 2; ++t) {
            const float4 q0 = *(const float4*)(qr[t] + ks * 32);
            const float4 q1 = *(const float4*)(qr[t] + ks * 32 + 4);
            const float av[8] = {q0.x, q0.y, q0.z, q0.w, q1.x, q1.y, q1.z, q1.w};
#pragma unroll
            for (int j = 0; j < 8; ++j) {
                const unsigned short hi = f2bf(av[j]);
                a_hi[t][j] = (short)hi;
                a_lo[t][j] = (short)f2bf(av[j] - bf2f(hi));
            }
        }

#pragma unroll
        for (int i = 0; i < 5; ++i) {
            const int nt = wt + 4 * i;
            if (nt < 18) {
                const bf16x8 b_hi = *(const bf16x8*)(Bs + (nt * 64 + g * 16 + c) * 8);
                const bf16x8 b_lo = *(const bf16x8*)(Bs + (1152 + nt * 64 + g * 16 + c) * 8);
#pragma unroll
                for (int t = 0; t < 2; ++t) {
                    acc[t][i] = __builtin_amdgcn_mfma_f32_16x16x32_bf16(
                        a_hi[t], b_hi, acc[t][i], 0, 0, 0);
                    acc[t][i] = __builtin_amdgcn_mfma_f32_16x16x32_bf16(
                        a_lo[t], b_hi, acc[t][i], 0, 0, 0);
                    acc[t][i] = __builtin_amdgcn_mfma_f32_16x16x32_bf16(
                        a_hi[t], b_lo, acc[t][i], 0, 0, 0);
                }
            }
        }
        __syncthreads();
    }

#pragma unroll
    for (int i = 0; i < 5; ++i) {
        const int nt = wt + 4 * i;
        if (nt < 18) {
            const int col = nt * 16 + c;
#pragma unroll
            for (int t = 0; t < 2; ++t)
#pragma unroll
                for (int j = 0; j < 4; ++j)
                    logits[(size_t)(row0 + t * 16 + 4 * g + j) * 288 + col] =
                        acc[t][i][j];
        }
    }
}

// ---------------------------------------------------------------------------
// K1: FUSED vproj + qgemm.  Independent work merged into one launch so the
// latency-bound vproj blocks and MFMA/LDS-bound qgemm blocks co-reside and
// fill each other's stalls.  3:2 interleave (1250 qgemm : 828 vproj).
// Branch is block-uniform -> per-branch __syncthreads is safe.
// ---------------------------------------------------------------------------
__global__ __launch_bounds__(256) void vq_kernel(
    const float* __restrict__ feat0, const float* __restrict__ feat1,
    const float* __restrict__ feat2,
    const unsigned short* __restrict__ WvTh, const unsigned short* __restrict__ WvTl,
    const float* __restrict__ bv,
    unsigned short* __restrict__ v0, unsigned short* __restrict__ v1,
    unsigned short* __restrict__ v2,
    const float* __restrict__ query,
    const unsigned short* __restrict__ WTh,
    float* __restrict__ logits)
{
    __shared__ __align__(16) char SH[36864];
    const int id = blockIdx.x;
    const int g5 = id / 5;
    const int r5 = id - g5 * 5;
    if (r5 < 3) {
        const int qb = g5 * 3 + r5;
        if (qb < 1250)
            qgemm_body(query, WTh, logits, qb, (short*)SH);
    } else {
        const int vb = g5 * 2 + (r5 - 3);
        if (vb < 828)
            vproj_body(feat0, feat1, feat2, WvTh, WvTl, bv, v0, v1, v2,
                       vb, (short*)SH);
    }
}

// ---------------------------------------------------------------------------
// K3: sampler, cooperative epilogue (R14) + XCD-aware 1D grid (R15).
// ---------------------------------------------------------------------------
__global__ __launch_bounds__(256) void sample_kernel(
    const float* __restrict__ logits,
    const float* __restrict__ ref,
    const float* __restrict__ boff, const float* __restrict__ battn,
    const unsigned short* __restrict__ v0,
    const unsigned short* __restrict__ v1,
    const unsigned short* __restrict__ v2,
    unsigned short* __restrict__ outp)
{
    const int tid  = threadIdx.x;
    const int wv   = tid >> 6;
    const int lane = tid & 63;
    const int qd   = lane >> 3;
    const int co   = lane & 7;

    const int id = blockIdx.x;           // 0..10015
    const int h  = id & 7;               // XCD key
    const int m  = id >> 3;              // 0..1251
    const int b  = m / 313;
    const int n  = m - b * 313;
    const int q  = n * 32 + wv * 8 + qd;
    if (q >= QLEN) return;               // whole 8-lane group exits together
    const int qq = b * QLEN + q;

    const float* lgq  = logits + (size_t)qq * 288;
    const int bpbase  = (lane & 56) * 4;     // byte index of group lane 0

    // ---- distributed softmax over the 12 attn logits ----
    const float at0 = lgq[192 + h * 12 + co] + battn[h * 12 + co];
    const float at1 = (co < 4)
        ? lgq[192 + h * 12 + 8 + co] + battn[h * 12 + 8 + co] : -1e30f;
    float mx = fmaxf(at0, at1);
#pragma unroll
    for (int msk = 1; msk < 8; msk <<= 1)
        mx = fmaxf(mx, __shfl_xor(mx, msk, 8));
    const float e0 = __expf(at0 - mx);
    const float e1 = (co < 4) ? __expf(at1 - mx) : 0.f;
    float sm = e0 + e1;
#pragma unroll
    for (int msk = 1; msk < 8; msk <<= 1)
        sm += __shfl_xor(sm, msk, 8);
    const float inv = 1.f / sm;

    const float refx = ref[(size_t)qq * 2 + 0];
    const float refy = ref[(size_t)qq * 2 + 1];

    // ---- owner: corner data for points co (slot 0) and co+8 (slot 1) ----
    int   oidx[2][4];
    float owt [2][4];
#pragma unroll
    for (int s = 0; s < 2; ++s) {
        const int pt = co + 8 * s;                   // slot1 valid only co<4
        const int l  = (s == 0) ? (co >> 2) : 2;
        const int Wl = (l == 0) ? 100 : (l == 1) ? 50 : 25;
        const float aw  = (s ? e1 : e0) * inv;
        const float lgx = lgq[h * 24 + 2 * pt]     + boff[h * 24 + 2 * pt];
        const float lgy = lgq[h * 24 + 2 * pt + 1] + boff[h * 24 + 2 * pt + 1];
        const float x = (refx + 0.5f * tanh_fast(lgx)) * (float)Wl - 0.5f;
        const float y = (refy + 0.5f * tanh_fast(lgy)) * (float)Wl - 0.5f;
        const float xf = floorf(x), yf = floorf(y);
        const int   x0i = (int)xf, y0i = (int)yf;
        const float wx = x - xf, wy = y - yf;
#pragma unroll
        for (int cy = 0; cy < 2; ++cy) {
#pragma unroll
            for (int cx = 0; cx < 2; ++cx) {
                const int xi = x0i + cx, yi = y0i + cy;
                const bool valid = (xi >= 0) & (xi < Wl) & (yi >= 0) & (yi < Wl);
                const int xc = min(max(xi, 0), Wl - 1);
                const int yc = min(max(yi, 0), Wl - 1);
                oidx[s][cy * 2 + cx] = yc * Wl + xc;
                owt [s][cy * 2 + cx] = valid
                    ? aw * (cx ? wx : 1.f - wx) * (cy ? wy : 1.f - wy) : 0.f;
            }
        }
    }

    // ---- gather: per level, broadcast owners' corner data via bpermute ----
    float o0 = 0.f, o1 = 0.f, o2 = 0.f, o3 = 0.f;

#pragma unroll
    for (int l = 0; l < 3; ++l) {
        const int Wl = (l == 0) ? 100 : (l == 1) ? 50 : 25;
        const int HW = Wl * Wl;
        const unsigned short* vh =
            ((l == 0) ? v0 : (l == 1) ? v1 : v2) +
            ((size_t)(b * NHEAD + h) * HW) * 32;

#pragma unroll
        for (int p = 0; p < 4; ++p) {
            const int src  = (l == 2) ? p : l * 4 + p;
            const int slot = (l == 2) ? 1 : 0;
#pragma unroll
            for (int k = 0; k < 4; ++k) {
                const int ci = __builtin_amdgcn_ds_bpermute(
                    bpbase + 4 * src, oidx[slot][k]);
                const int cwbits = __builtin_amdgcn_ds_bpermute(
                    bpbase + 4 * src, __float_as_int(owt[slot][k]));
                const float cw = __int_as_float(cwbits);
                const ushort4 u = *(const ushort4*)(vh + (size_t)ci * 32 + co * 4);
                o0 = fmaf(cw, bf2f(u.x), o0);
                o1 = fmaf(cw, bf2f(u.y), o1);
                o2 = fmaf(cw, bf2f(u.z), o2);
                o3 = fmaf(cw, bf2f(u.w), o3);
            }
        }
    }

    unsigned int lo = (unsigned int)f2bf(o0) | ((unsigned int)f2bf(o1) << 16);
    unsigned int hi = (unsigned int)f2bf(o2) | ((unsigned int)f2bf(o3) << 16);
    *(uint2*)(outp + (size_t)qq * 256 + h * 32 + co * 4) = make_uint2(lo, hi);
}

// ---------------------------------------------------------------------------
// K4: output projection via bf16 MFMA (validated R7).
// ---------------------------------------------------------------------------
__global__ __launch_bounds__(256) void outproj_kernel(
    const unsigned short* __restrict__ A, const unsigned short* __restrict__ WoT,
    const float* __restrict__ bo, float* __restrict__ out)
{
    const int tid  = threadIdx.x;
    const int wave = tid >> 6;
    const int lane = tid & 63;
    const int c    = lane & 15;
    const int g    = lane >> 4;
    const int row0 = blockIdx.x * 64;
    const int n0   = wave * 64;

    f32x4 acc[4][4];
#pragma unroll
    for (int mt = 0; mt < 4; ++mt)
#pragma unroll
        for (int nt = 0; nt < 4; ++nt)
            acc[mt][nt] = (f32x4){0.f, 0.f, 0.f, 0.f};

    const unsigned short* Abase = A   + (size_t)(row0 + c) * 256 + 8 * g;
    const unsigned short* Bbase = WoT + (size_t)(n0   + c) * 256 + 8 * g;

#pragma unroll
    for (int ks = 0; ks < 8; ++ks) {
        bf16x8 a[4], bvec[4];
#pragma unroll
        for (int t = 0; t < 4; ++t) {
            a[t]    = *(const bf16x8*)(Abase + (size_t)t * 16 * 256 + ks * 32);
            bvec[t] = *(const bf16x8*)(Bbase + (size_t)t * 16 * 256 + ks * 32);
        }
#pragma unroll
        for (int mt = 0; mt < 4; ++mt)
#pragma unroll
            for (int nt = 0; nt < 4; ++nt)
                acc[mt][nt] = __builtin_amdgcn_mfma_f32_16x16x32_bf16(
                    a[mt], bvec[nt], acc[mt][nt], 0, 0, 0);
    }

#pragma unroll
    for (int nt = 0; nt < 4; ++nt) {
        const int col  = n0 + nt * 16 + c;
        const float bias = bo[col];
#pragma unroll
        for (int mt = 0; mt < 4; ++mt) {
#pragma unroll
            for (int j = 0; j < 4; ++j) {
                const int row = row0 + mt * 16 + g * 4 + j;
                out[(size_t)row * 256 + col] = acc[mt][nt][j] + bias;
            }
        }
    }
}

// ---------------------------------------------------------------------------
extern "C" void kernel_launch(void* const* d_in, const int* in_sizes, int n_in,
                              void* d_out, int out_size, void* d_ws, size_t ws_size,
                              hipStream_t stream)
{
    const float* query  = (const float*)d_in[0];
    const float* value0 = (const float*)d_in[1];
    const float* value1 = (const float*)d_in[2];
    const float* value2 = (const float*)d_in[3];
    const float* refpts = (const float*)d_in[4];
    const float* Woff   = (const float*)d_in[5];
    const float* boff   = (const float*)d_in[6];
    const float* Wattn  = (const float*)d_in[7];
    const float* battn  = (const float*)d_in[8];
    const float* Wval   = (const float*)d_in[9];
    const float* bval   = (const float*)d_in[10];
    const float* Wout   = (const float*)d_in[11];
    const float* bout   = (const float*)d_in[12];
    float* out = (float*)d_out;

    float*          logits = (float*)d_ws;
    unsigned short* v0   = (unsigned short*)(logits + (size_t)NQ * 288);
    unsigned short* v1   = v0 + (size_t)BATCH * 10000 * 256;
    unsigned short* v2   = v1 + (size_t)BATCH * 2500  * 256;
    unsigned short* A_bf = v2 + (size_t)BATCH * 625   * 256;
    unsigned short* WoT  = A_bf + (size_t)NQ * 256;
    unsigned short* WTh  = WoT + (size_t)256 * 256;
    unsigned short* WTl  = WTh + (size_t)288 * 256;   // contiguous after WTh
    unsigned short* WvTh = WTl + (size_t)288 * 256;
    unsigned short* WvTl = WvTh + (size_t)256 * 256;

    wprep_kernel<<<800, 256, 0, stream>>>(Woff, Wattn, Wout, Wval,
                                          WTh, WTl, WoT, WvTh, WvTl);

    vq_kernel<<<2082, 256, 0, stream>>>(
        value0, value1, value2, WvTh, WvTl, bval, v0, v1, v2,
        query, WTh, logits);

    sample_kernel<<<8 * 313 * BATCH, 256, 0, stream>>>(
        logits, refpts, boff, battn, v0, v1, v2, A_bf);

    outproj_kernel<<<NQ / 64, 256, 0, stream>>>(A_bf, WoT, bout, out);
}

// Round 18
// 213.988 us; speedup vs baseline: 1.1553x; 1.0305x over previous
//
#include <hip/hip_runtime.h>
#include <math.h>

#define DMODEL 256
#define NHEAD 8
#define NLVL 3
#define NPTS 4
#define HDIM 32
#define QLEN 10000
#define BATCH 4
#define NQ (BATCH * QLEN)

typedef __attribute__((ext_vector_type(8))) short bf16x8;
typedef __attribute__((ext_vector_type(4))) float f32x4;

__device__ __forceinline__ float tanh_fast(float x)
{
    const float ax = fabsf(x);
    const float e  = __expf(-2.f * ax);
    const float t  = (1.f - e) / (1.f + e);
    return copysignf(t, x);
}

__device__ __forceinline__ unsigned short f2bf(float f)
{
    unsigned int u = __float_as_uint(f);
    u = (u + 0x7FFFu + ((u >> 16) & 1u)) >> 16;
    return (unsigned short)u;
}

__device__ __forceinline__ float bf2f(unsigned short s)
{
    return __uint_as_float(((unsigned int)s) << 16);
}

// ---------------------------------------------------------------------------
// K0: weight prep (once).  Writes PRE-SWIZZLED layouts so the GEMM kernels'
// LDS staging (qgemm) and fragment loads (vproj) are lane-linear:
//   WTs : [ks][hl][nt][g][c][8]   (qgemm B, hi+lo)   147456 shorts
//   WoT : [n][k] bf16             (outproj B)         65536 shorts
//   WvS : [nc][ks][g][c][8]       (vproj B, hi & lo)  65536 shorts each
// ---------------------------------------------------------------------------
__global__ __launch_bounds__(256) void wprep_kernel(
    const float* __restrict__ Woff, const float* __restrict__ Wattn,
    const float* __restrict__ Wout, const float* __restrict__ Wval,
    unsigned short* __restrict__ WTs, unsigned short* __restrict__ WoT,
    unsigned short* __restrict__ WvSh, unsigned short* __restrict__ WvSl)
{
    const int k  = threadIdx.x;
    const int n  = blockIdx.x;
    const int ks = k >> 5;
    const int g  = (k >> 3) & 3;
    const int j  = k & 7;
    if (n < 288) {
        const float w = (n < 192) ? Woff[(size_t)k * 192 + n]
                                  : Wattn[(size_t)k * 96 + (n - 192)];
        const unsigned short hi = f2bf(w);
        const unsigned short lo = f2bf(w - bf2f(hi));
        const int nt = n >> 4, c = n & 15;
        const size_t base = (size_t)ks * 18432 + (size_t)nt * 512
                          + g * 128 + c * 8 + j;
        WTs[base]        = hi;    // hl = 0
        WTs[base + 9216] = lo;    // hl = 1 (offset 9216 SHORTS = 1152 slots)
    } else if (n < 544) {
        const int nn = n - 288;
        WoT[(size_t)nn * 256 + k] = f2bf(Wout[(size_t)k * 256 + nn]);
    } else {
        const int nn = n - 544;
        const float w = Wval[(size_t)k * 256 + nn];
        const unsigned short hi = f2bf(w);
        const int nc = nn >> 4, c = nn & 15;
        const size_t idx = (size_t)nc * 4096 + (size_t)ks * 512
                         + g * 128 + c * 8 + j;
        WvSh[idx] = hi;
        WvSl[idx] = f2bf(w - bf2f(hi));
    }
}

// ---------------------------------------------------------------------------
// K1: value projection via bf16 MFMA, 32-POS TILES (1648 blocks, 16KB LDS)
// for latency hiding.  Output HEAD-MAJOR v[b][h][pos][32].  B-fragments
// read from pre-swizzled WvS: each wave-instr load is 1KB contiguous.
// ---------------------------------------------------------------------------
__global__ __launch_bounds__(256) void vproj_kernel(
    const float* __restrict__ feat0, const float* __restrict__ feat1,
    const float* __restrict__ feat2,
    const unsigned short* __restrict__ WvSh, const unsigned short* __restrict__ WvSl,
    const float* __restrict__ bv,
    unsigned short* __restrict__ v0, unsigned short* __restrict__ v1,
    unsigned short* __restrict__ v2)
{
    __shared__ short As[32 * 32 * 8];   // [kc][pos][8] = 16 KB

    const int bx = blockIdx.x;
    const int b  = blockIdx.y;

    const float* feat;
    unsigned short* vout;
    int HW, pos0;
    if (bx < 313)      { feat = feat0; vout = v0; HW = 10000; pos0 = bx * 32; }
    else if (bx < 392) { feat = feat1; vout = v1; HW = 2500;  pos0 = (bx - 313) * 32; }
    else               { feat = feat2; vout = v2; HW = 625;   pos0 = (bx - 392) * 32; }

    const int tid  = threadIdx.x;
    const int wv   = tid >> 6;
    const int lane = tid & 63;
    const int c    = lane & 15;
    const int g    = lane >> 4;

    // ---- stage feat[k][pos0..pos0+32) -> As bf16 ----
    const int sp  = tid & 31;           // pos within tile
    const int kc8 = tid >> 5;           // 0..7
    const bool pv = (pos0 + sp) < HW;
    const float* fcol = feat + (size_t)b * DMODEL * HW + pos0 + sp;

#pragma unroll
    for (int i = 0; i < 4; ++i) {
        const int kc = kc8 + 8 * i;     // 0..31
        short h8[8];
#pragma unroll
        for (int j = 0; j < 8; ++j) {
            const float f = pv ? fcol[(size_t)(kc * 8 + j) * HW] : 0.f;
            h8[j] = (short)f2bf(f);
        }
        *(bf16x8*)&As[((size_t)kc * 32 + sp) * 8] = *(bf16x8*)h8;
    }
    __syncthreads();

    f32x4 acc[2][4];
#pragma unroll
    for (int mt = 0; mt < 2; ++mt)
#pragma unroll
        for (int nt = 0; nt < 4; ++nt)
            acc[mt][nt] = (f32x4){0.f, 0.f, 0.f, 0.f};

#pragma unroll
    for (int ks = 0; ks < 8; ++ks) {
        bf16x8 a[2];
#pragma unroll
        for (int mt = 0; mt < 2; ++mt)
            a[mt] = *(const bf16x8*)&As[((size_t)(ks * 4 + g) * 32 + mt * 16 + c) * 8];
        bf16x8 bh[4], bl[4];
#pragma unroll
        for (int nt = 0; nt < 4; ++nt) {
            const size_t off = (size_t)(wv * 4 + nt) * 4096 + (size_t)ks * 512
                             + g * 128 + c * 8;
            bh[nt] = *(const bf16x8*)(WvSh + off);
            bl[nt] = *(const bf16x8*)(WvSl + off);
        }
#pragma unroll
        for (int mt = 0; mt < 2; ++mt)
#pragma unroll
            for (int nt = 0; nt < 4; ++nt) {
                acc[mt][nt] = __builtin_amdgcn_mfma_f32_16x16x32_bf16(
                    a[mt], bh[nt], acc[mt][nt], 0, 0, 0);
                acc[mt][nt] = __builtin_amdgcn_mfma_f32_16x16x32_bf16(
                    a[mt], bl[nt], acc[mt][nt], 0, 0, 0);
            }
    }

    unsigned short* vbp = vout + (size_t)b * NHEAD * HW * 32;
#pragma unroll
    for (int nt = 0; nt < 4; ++nt) {
        const int col  = wv * 64 + nt * 16 + c;
        const int hh   = col >> 5;
        const int cc   = col & 31;
        const float bias = bv[col];
#pragma unroll
        for (int mt = 0; mt < 2; ++mt) {
#pragma unroll
            for (int j = 0; j < 4; ++j) {
                const int p = mt * 16 + g * 4 + j;
                if (pos0 + p < HW)
                    vbp[((size_t)hh * HW + pos0 + p) * 32 + cc] =
                        f2bf(acc[mt][nt][j] + bias);
            }
        }
    }
}

// ---------------------------------------------------------------------------
// K2: query-side GEMM (validated R13) with LINEAR staging from pre-swizzled
// WTs: per ks the 36.9KB B slice is a straight memcpy (conflict-free writes,
// perfectly coalesced loads).  Writes raw logits f32.
// ---------------------------------------------------------------------------
__global__ __launch_bounds__(256) void qgemm_kernel(
    const float* __restrict__ query,
    const unsigned short* __restrict__ WTs,
    float* __restrict__ logits)
{
    __shared__ __align__(16) short Bs[2 * 18 * 64 * 8];   // 18432 shorts = 36864 B

    const int tid  = threadIdx.x;
    const int wt   = tid >> 6;
    const int lane = tid & 63;
    const int c    = lane & 15;
    const int g    = lane >> 4;
    const int row0 = blockIdx.x * 32;

    const float* qr[2];
#pragma unroll
    for (int t = 0; t < 2; ++t)
        qr[t] = query + (size_t)(row0 + t * 16 + c) * 256 + 8 * g;

    f32x4 acc[2][5];
#pragma unroll
    for (int t = 0; t < 2; ++t)
#pragma unroll
        for (int i = 0; i < 5; ++i) acc[t][i] = (f32x4){0.f, 0.f, 0.f, 0.f};

    for (int ks = 0; ks < 8; ++ks) {
        // ---- linear stage: 2304 chunks of 16B, 9 per thread ----
        const unsigned short* src = WTs + (size_t)ks * 18432;
#pragma unroll
        for (int i = 0; i < 9; ++i) {
            const int ch = tid + 256 * i;
            *(bf16x8*)(Bs + (size_t)ch * 8) = *(const bf16x8*)(src + (size_t)ch * 8);
        }
        __syncthreads();

        bf16x8 a_hi[2], a_lo[2];
#pragma unroll
        for (int t = 0; t < 2; ++t) {
            const float4 q0 = *(const float4*)(qr[t] + ks * 32);
            const float4 q1 = *(const float4*)(qr[t] + ks * 32 + 4);
            const float av[8] = {q0.x, q0.y, q0.z, q0.w, q1.x, q1.y, q1.z, q1.w};
#pragma unroll
            for (int j = 0; j < 8; ++j) {
                const unsigned short hi = f2bf(av[j]);
                a_hi[t][j] = (short)hi;
                a_lo[t][j] = (short)f2bf(av[j] - bf2f(hi));
            }
        }

#pragma unroll
        for (int i = 0; i < 5; ++i) {
            const int nt = wt + 4 * i;
            if (nt < 18) {
                // slot offsets: hl=0 at 0, hl=1 at 1152 slots (=9216 shorts)
                const bf16x8 b_hi = *(const bf16x8*)(Bs + (nt * 64 + g * 16 + c) * 8);
                const bf16x8 b_lo = *(const bf16x8*)(Bs + (1152 + nt * 64 + g * 16 + c) * 8);
#pragma unroll
                for (int t = 0; t < 2; ++t) {
                    acc[t][i] = __builtin_amdgcn_mfma_f32_16x16x32_bf16(
                        a_hi[t], b_hi, acc[t][i], 0, 0, 0);
                    acc[t][i] = __builtin_amdgcn_mfma_f32_16x16x32_bf16(
                        a_lo[t], b_hi, acc[t][i], 0, 0, 0);
                    acc[t][i] = __builtin_amdgcn_mfma_f32_16x16x32_bf16(
                        a_hi[t], b_lo, acc[t][i], 0, 0, 0);
                }
            }
        }
        __syncthreads();
    }

#pragma unroll
    for (int i = 0; i < 5; ++i) {
        const int nt = wt + 4 * i;
        if (nt < 18) {
            const int col = nt * 16 + c;
#pragma unroll
            for (int t = 0; t < 2; ++t)
#pragma unroll
                for (int j = 0; j < 4; ++j)
                    logits[(size_t)(row0 + t * 16 + 4 * g + j) * 288 + col] =
                        acc[t][i][j];
        }
    }
}

// ---------------------------------------------------------------------------
// K3: sampler, cooperative epilogue (R14) + XCD-aware 1D grid (R15).
// ---------------------------------------------------------------------------
__global__ __launch_bounds__(256) void sample_kernel(
    const float* __restrict__ logits,
    const float* __restrict__ ref,
    const float* __restrict__ boff, const float* __restrict__ battn,
    const unsigned short* __restrict__ v0,
    const unsigned short* __restrict__ v1,
    const unsigned short* __restrict__ v2,
    unsigned short* __restrict__ outp)
{
    const int tid  = threadIdx.x;
    const int wv   = tid >> 6;
    const int lane = tid & 63;
    const int qd   = lane >> 3;
    const int co   = lane & 7;

    const int id = blockIdx.x;           // 0..10015
    const int h  = id & 7;               // XCD key
    const int m  = id >> 3;              // 0..1251
    const int b  = m / 313;
    const int n  = m - b * 313;
    const int q  = n * 32 + wv * 8 + qd;
    if (q >= QLEN) return;               // whole 8-lane group exits together
    const int qq = b * QLEN + q;

    const float* lgq  = logits + (size_t)qq * 288;
    const int bpbase  = (lane & 56) * 4;     // byte index of group lane 0

    // ---- distributed softmax over the 12 attn logits ----
    const float at0 = lgq[192 + h * 12 + co] + battn[h * 12 + co];
    const float at1 = (co < 4)
        ? lgq[192 + h * 12 + 8 + co] + battn[h * 12 + 8 + co] : -1e30f;
    float mx = fmaxf(at0, at1);
#pragma unroll
    for (int msk = 1; msk < 8; msk <<= 1)
        mx = fmaxf(mx, __shfl_xor(mx, msk, 8));
    const float e0 = __expf(at0 - mx);
    const float e1 = (co < 4) ? __expf(at1 - mx) : 0.f;
    float sm = e0 + e1;
#pragma unroll
    for (int msk = 1; msk < 8; msk <<= 1)
        sm += __shfl_xor(sm, msk, 8);
    const float inv = 1.f / sm;

    const float refx = ref[(size_t)qq * 2 + 0];
    const float refy = ref[(size_t)qq * 2 + 1];

    // ---- owner: corner data for points co (slot 0) and co+8 (slot 1) ----
    int   oidx[2][4];
    float owt [2][4];
#pragma unroll
    for (int s = 0; s < 2; ++s) {
        const int pt = co + 8 * s;                   // slot1 valid only co<4
        const int l  = (s == 0) ? (co >> 2) : 2;
        const int Wl = (l == 0) ? 100 : (l == 1) ? 50 : 25;
        const float aw  = (s ? e1 : e0) * inv;
        const float lgx = lgq[h * 24 + 2 * pt]     + boff[h * 24 + 2 * pt];
        const float lgy = lgq[h * 24 + 2 * pt + 1] + boff[h * 24 + 2 * pt + 1];
        const float x = (refx + 0.5f * tanh_fast(lgx)) * (float)Wl - 0.5f;
        const float y = (refy + 0.5f * tanh_fast(lgy)) * (float)Wl - 0.5f;
        const float xf = floorf(x), yf = floorf(y);
        const int   x0i = (int)xf, y0i = (int)yf;
        const float wx = x - xf, wy = y - yf;
#pragma unroll
        for (int cy = 0; cy < 2; ++cy) {
#pragma unroll
            for (int cx = 0; cx < 2; ++cx) {
                const int xi = x0i + cx, yi = y0i + cy;
                const bool valid = (xi >= 0) & (xi < Wl) & (yi >= 0) & (yi < Wl);
                const int xc = min(max(xi, 0), Wl - 1);
                const int yc = min(max(yi, 0), Wl - 1);
                oidx[s][cy * 2 + cx] = yc * Wl + xc;
                owt [s][cy * 2 + cx] = valid
                    ? aw * (cx ? wx : 1.f - wx) * (cy ? wy : 1.f - wy) : 0.f;
            }
        }
    }

    // ---- gather: per level, broadcast owners' corner data via bpermute ----
    float o0 = 0.f, o1 = 0.f, o2 = 0.f, o3 = 0.f;

#pragma unroll
    for (int l = 0; l < 3; ++l) {
        const int Wl = (l == 0) ? 100 : (l == 1) ? 50 : 25;
        const int HW = Wl * Wl;
        const unsigned short* vh =
            ((l == 0) ? v0 : (l == 1) ? v1 : v2) +
            ((size_t)(b * NHEAD + h) * HW) * 32;

#pragma unroll
        for (int p = 0; p < 4; ++p) {
            const int src  = (l == 2) ? p : l * 4 + p;
            const int slot = (l == 2) ? 1 : 0;
#pragma unroll
            for (int k = 0; k < 4; ++k) {
                const int ci = __builtin_amdgcn_ds_bpermute(
                    bpbase + 4 * src, oidx[slot][k]);
                const int cwbits = __builtin_amdgcn_ds_bpermute(
                    bpbase + 4 * src, __float_as_int(owt[slot][k]));
                const float cw = __int_as_float(cwbits);
                const ushort4 u = *(const ushort4*)(vh + (size_t)ci * 32 + co * 4);
                o0 = fmaf(cw, bf2f(u.x), o0);
                o1 = fmaf(cw, bf2f(u.y), o1);
                o2 = fmaf(cw, bf2f(u.z), o2);
                o3 = fmaf(cw, bf2f(u.w), o3);
            }
        }
    }

    unsigned int lo = (unsigned int)f2bf(o0) | ((unsigned int)f2bf(o1) << 16);
    unsigned int hi = (unsigned int)f2bf(o2) | ((unsigned int)f2bf(o3) << 16);
    *(uint2*)(outp + (size_t)qq * 256 + h * 32 + co * 4) = make_uint2(lo, hi);
}

// ---------------------------------------------------------------------------
// K4: output projection via bf16 MFMA (validated R7).
// ---------------------------------------------------------------------------
__global__ __launch_bounds__(256) void outproj_kernel(
    const unsigned short* __restrict__ A, const unsigned short* __restrict__ WoT,
    const float* __restrict__ bo, float* __restrict__ out)
{
    const int tid  = threadIdx.x;
    const int wave = tid >> 6;
    const int lane = tid & 63;
    const int c    = lane & 15;
    const int g    = lane >> 4;
    const int row0 = blockIdx.x * 64;
    const int n0   = wave * 64;

    f32x4 acc[4][4];
#pragma unroll
    for (int mt = 0; mt < 4; ++mt)
#pragma unroll
        for (int nt = 0; nt < 4; ++nt)
            acc[mt][nt] = (f32x4){0.f, 0.f, 0.f, 0.f};

    const unsigned short* Abase = A   + (size_t)(row0 + c) * 256 + 8 * g;
    const unsigned short* Bbase = WoT + (size_t)(n0   + c) * 256 + 8 * g;

#pragma unroll
    for (int ks = 0; ks < 8; ++ks) {
        bf16x8 a[4], bvec[4];
#pragma unroll
        for (int t = 0; t < 4; ++t) {
            a[t]    = *(const bf16x8*)(Abase + (size_t)t * 16 * 256 + ks * 32);
            bvec[t] = *(const bf16x8*)(Bbase + (size_t)t * 16 * 256 + ks * 32);
        }
#pragma unroll
        for (int mt = 0; mt < 4; ++mt)
#pragma unroll
            for (int nt = 0; nt < 4; ++nt)
                acc[mt][nt] = __builtin_amdgcn_mfma_f32_16x16x32_bf16(
                    a[mt], bvec[nt], acc[mt][nt], 0, 0, 0);
    }

#pragma unroll
    for (int nt = 0; nt < 4; ++nt) {
        const int col  = n0 + nt * 16 + c;
        const float bias = bo[col];
#pragma unroll
        for (int mt = 0; mt < 4; ++mt) {
#pragma unroll
            for (int j = 0; j < 4; ++j) {
                const int row = row0 + mt * 16 + g * 4 + j;
                out[(size_t)row * 256 + col] = acc[mt][nt][j] + bias;
            }
        }
    }
}

// ---------------------------------------------------------------------------
extern "C" void kernel_launch(void* const* d_in, const int* in_sizes, int n_in,
                              void* d_out, int out_size, void* d_ws, size_t ws_size,
                              hipStream_t stream)
{
    const float* query  = (const float*)d_in[0];
    const float* value0 = (const float*)d_in[1];
    const float* value1 = (const float*)d_in[2];
    const float* value2 = (const float*)d_in[3];
    const float* refpts = (const float*)d_in[4];
    const float* Woff   = (const float*)d_in[5];
    const float* boff   = (const float*)d_in[6];
    const float* Wattn  = (const float*)d_in[7];
    const float* battn  = (const float*)d_in[8];
    const float* Wval   = (const float*)d_in[9];
    const float* bval   = (const float*)d_in[10];
    const float* Wout   = (const float*)d_in[11];
    const float* bout   = (const float*)d_in[12];
    float* out = (float*)d_out;

    // workspace: logits 46.08 + v 26.88 + A_bf 20.48 + weights ~0.7 = ~94.2 MB
    float*          logits = (float*)d_ws;
    unsigned short* v0   = (unsigned short*)(logits + (size_t)NQ * 288);
    unsigned short* v1   = v0 + (size_t)BATCH * 10000 * 256;
    unsigned short* v2   = v1 + (size_t)BATCH * 2500  * 256;
    unsigned short* A_bf = v2 + (size_t)BATCH * 625   * 256;
    unsigned short* WoT  = A_bf + (size_t)NQ * 256;
    unsigned short* WTs  = WoT + (size_t)256 * 256;        // 147456 shorts
    unsigned short* WvSh = WTs + (size_t)147456;
    unsigned short* WvSl = WvSh + (size_t)65536;

    wprep_kernel<<<800, 256, 0, stream>>>(Woff, Wattn, Wout, Wval,
                                          WTs, WoT, WvSh, WvSl);

    vproj_kernel<<<dim3(412, BATCH), 256, 0, stream>>>(
        value0, value1, value2, WvSh, WvSl, bval, v0, v1, v2);

    qgemm_kernel<<<NQ / 32, 256, 0, stream>>>(query, WTs, logits);

    sample_kernel<<<8 * 313 * BATCH, 256, 0, stream>>>(
        logits, refpts, boff, battn, v0, v1, v2, A_bf);

    outproj_kernel<<<NQ / 64, 256, 0, stream>>>(A_bf, WoT, bout, out);
}

// Round 19
// 199.081 us; speedup vs baseline: 1.2418x; 1.0749x over previous
//
#include <hip/hip_runtime.h>
#include <math.h>

#define DMODEL 256
#define NHEAD 8
#define NLVL 3
#define NPTS 4
#define HDIM 32
#define QLEN 10000
#define BATCH 4
#define NQ (BATCH * QLEN)

typedef __attribute__((ext_vector_type(8))) short bf16x8;
typedef __attribute__((ext_vector_type(4))) float f32x4;

__device__ __forceinline__ float tanh_fast(float x)
{
    const float ax = fabsf(x);
    const float e  = __expf(-2.f * ax);
    const float t  = (1.f - e) / (1.f + e);
    return copysignf(t, x);
}

__device__ __forceinline__ unsigned short f2bf(float f)
{
    unsigned int u = __float_as_uint(f);
    u = (u + 0x7FFFu + ((u >> 16) & 1u)) >> 16;
    return (unsigned short)u;
}

__device__ __forceinline__ float bf2f(unsigned short s)
{
    return __uint_as_float(((unsigned int)s) << 16);
}

// ---------------------------------------------------------------------------
// K0: weight prep (once).  Pre-swizzled layouts (validated R18):
//   WTs : [ks][hl][nt][g][c][8]   (qgemm B, hi+lo)   147456 shorts
//   WoT : [n][k] bf16             (outproj B)         65536 shorts
//   WvS : [nc][ks][g][c][8]       (vproj B, hi & lo)  65536 shorts each
// ---------------------------------------------------------------------------
__global__ __launch_bounds__(256) void wprep_kernel(
    const float* __restrict__ Woff, const float* __restrict__ Wattn,
    const float* __restrict__ Wout, const float* __restrict__ Wval,
    unsigned short* __restrict__ WTs, unsigned short* __restrict__ WoT,
    unsigned short* __restrict__ WvSh, unsigned short* __restrict__ WvSl)
{
    const int k  = threadIdx.x;
    const int n  = blockIdx.x;
    const int ks = k >> 5;
    const int g  = (k >> 3) & 3;
    const int j  = k & 7;
    if (n < 288) {
        const float w = (n < 192) ? Woff[(size_t)k * 192 + n]
                                  : Wattn[(size_t)k * 96 + (n - 192)];
        const unsigned short hi = f2bf(w);
        const unsigned short lo = f2bf(w - bf2f(hi));
        const int nt = n >> 4, c = n & 15;
        const size_t base = (size_t)ks * 18432 + (size_t)nt * 512
                          + g * 128 + c * 8 + j;
        WTs[base]        = hi;    // hl = 0
        WTs[base + 9216] = lo;    // hl = 1 (offset 9216 shorts)
    } else if (n < 544) {
        const int nn = n - 288;
        WoT[(size_t)nn * 256 + k] = f2bf(Wout[(size_t)k * 256 + nn]);
    } else {
        const int nn = n - 544;
        const float w = Wval[(size_t)k * 256 + nn];
        const unsigned short hi = f2bf(w);
        const int nc = nn >> 4, c = nn & 15;
        const size_t idx = (size_t)nc * 4096 + (size_t)ks * 512
                         + g * 128 + c * 8 + j;
        WvSh[idx] = hi;
        WvSl[idx] = f2bf(w - bf2f(hi));
    }
}

// ---------------------------------------------------------------------------
// K1: value projection via bf16 MFMA, 32-pos tiles (validated R18).
// Output HEAD-MAJOR v[b][h][pos][32].
// ---------------------------------------------------------------------------
__global__ __launch_bounds__(256) void vproj_kernel(
    const float* __restrict__ feat0, const float* __restrict__ feat1,
    const float* __restrict__ feat2,
    const unsigned short* __restrict__ WvSh, const unsigned short* __restrict__ WvSl,
    const float* __restrict__ bv,
    unsigned short* __restrict__ v0, unsigned short* __restrict__ v1,
    unsigned short* __restrict__ v2)
{
    __shared__ short As[32 * 32 * 8];   // [kc][pos][8] = 16 KB

    const int bx = blockIdx.x;
    const int b  = blockIdx.y;

    const float* feat;
    unsigned short* vout;
    int HW, pos0;
    if (bx < 313)      { feat = feat0; vout = v0; HW = 10000; pos0 = bx * 32; }
    else if (bx < 392) { feat = feat1; vout = v1; HW = 2500;  pos0 = (bx - 313) * 32; }
    else               { feat = feat2; vout = v2; HW = 625;   pos0 = (bx - 392) * 32; }

    const int tid  = threadIdx.x;
    const int wv   = tid >> 6;
    const int lane = tid & 63;
    const int c    = lane & 15;
    const int g    = lane >> 4;

    const int sp  = tid & 31;
    const int kc8 = tid >> 5;
    const bool pv = (pos0 + sp) < HW;
    const float* fcol = feat + (size_t)b * DMODEL * HW + pos0 + sp;

#pragma unroll
    for (int i = 0; i < 4; ++i) {
        const int kc = kc8 + 8 * i;
        short h8[8];
#pragma unroll
        for (int j = 0; j < 8; ++j) {
            const float f = pv ? fcol[(size_t)(kc * 8 + j) * HW] : 0.f;
            h8[j] = (short)f2bf(f);
        }
        *(bf16x8*)&As[((size_t)kc * 32 + sp) * 8] = *(bf16x8*)h8;
    }
    __syncthreads();

    f32x4 acc[2][4];
#pragma unroll
    for (int mt = 0; mt < 2; ++mt)
#pragma unroll
        for (int nt = 0; nt < 4; ++nt)
            acc[mt][nt] = (f32x4){0.f, 0.f, 0.f, 0.f};

#pragma unroll
    for (int ks = 0; ks < 8; ++ks) {
        bf16x8 a[2];
#pragma unroll
        for (int mt = 0; mt < 2; ++mt)
            a[mt] = *(const bf16x8*)&As[((size_t)(ks * 4 + g) * 32 + mt * 16 + c) * 8];
        bf16x8 bh[4], bl[4];
#pragma unroll
        for (int nt = 0; nt < 4; ++nt) {
            const size_t off = (size_t)(wv * 4 + nt) * 4096 + (size_t)ks * 512
                             + g * 128 + c * 8;
            bh[nt] = *(const bf16x8*)(WvSh + off);
            bl[nt] = *(const bf16x8*)(WvSl + off);
        }
#pragma unroll
        for (int mt = 0; mt < 2; ++mt)
#pragma unroll
            for (int nt = 0; nt < 4; ++nt) {
                acc[mt][nt] = __builtin_amdgcn_mfma_f32_16x16x32_bf16(
                    a[mt], bh[nt], acc[mt][nt], 0, 0, 0);
                acc[mt][nt] = __builtin_amdgcn_mfma_f32_16x16x32_bf16(
                    a[mt], bl[nt], acc[mt][nt], 0, 0, 0);
            }
    }

    unsigned short* vbp = vout + (size_t)b * NHEAD * HW * 32;
#pragma unroll
    for (int nt = 0; nt < 4; ++nt) {
        const int col  = wv * 64 + nt * 16 + c;
        const int hh   = col >> 5;
        const int cc   = col & 31;
        const float bias = bv[col];
#pragma unroll
        for (int mt = 0; mt < 2; ++mt) {
#pragma unroll
            for (int j = 0; j < 4; ++j) {
                const int p = mt * 16 + g * 4 + j;
                if (pos0 + p < HW)
                    vbp[((size_t)hh * HW + pos0 + p) * 32 + cc] =
                        f2bf(acc[mt][nt][j] + bias);
            }
        }
    }
}

// ---------------------------------------------------------------------------
// K2: query-side GEMM, DIRECT-GLOBAL B (no LDS, no barriers).  32 rows/block,
// 4 waves col-split (nt = wt+4i).  B-fragments read straight from the
// pre-swizzled WTs (L2-resident, 1KB contiguous per wave-instr) -- the
// vproj-proven delivery.  Occupancy is wave-level (LDS=0), ks-loop fully
// unrolled so loads pipeline freely against MFMAs.
// ---------------------------------------------------------------------------
__global__ __launch_bounds__(256) void qgemm_kernel(
    const float* __restrict__ query,
    const unsigned short* __restrict__ WTs,
    float* __restrict__ logits)
{
    const int tid  = threadIdx.x;
    const int wt   = tid >> 6;
    const int lane = tid & 63;
    const int c    = lane & 15;
    const int g    = lane >> 4;
    const int row0 = blockIdx.x * 32;

    const float* qr[2];
#pragma unroll
    for (int t = 0; t < 2; ++t)
        qr[t] = query + (size_t)(row0 + t * 16 + c) * 256 + 8 * g;

    f32x4 acc[2][5];
#pragma unroll
    for (int t = 0; t < 2; ++t)
#pragma unroll
        for (int i = 0; i < 5; ++i) acc[t][i] = (f32x4){0.f, 0.f, 0.f, 0.f};

#pragma unroll
    for (int ks = 0; ks < 8; ++ks) {
        // ---- A fragments: query fp32 -> hi/lo bf16 split ----
        bf16x8 a_hi[2], a_lo[2];
#pragma unroll
        for (int t = 0; t < 2; ++t) {
            const float4 q0 = *(const float4*)(qr[t] + ks * 32);
            const float4 q1 = *(const float4*)(qr[t] + ks * 32 + 4);
            const float av[8] = {q0.x, q0.y, q0.z, q0.w, q1.x, q1.y, q1.z, q1.w};
#pragma unroll
            for (int j = 0; j < 8; ++j) {
                const unsigned short hi = f2bf(av[j]);
                a_hi[t][j] = (short)hi;
                a_lo[t][j] = (short)f2bf(av[j] - bf2f(hi));
            }
        }

        // ---- B fragments direct from WTs; 3-term MFMA ----
#pragma unroll
        for (int i = 0; i < 5; ++i) {
            const int nt = wt + 4 * i;
            if (nt < 18) {
                const unsigned short* bp = WTs + (size_t)ks * 18432
                                         + (size_t)nt * 512 + g * 128 + c * 8;
                const bf16x8 b_hi = *(const bf16x8*)bp;
                const bf16x8 b_lo = *(const bf16x8*)(bp + 9216);
#pragma unroll
                for (int t = 0; t < 2; ++t) {
                    acc[t][i] = __builtin_amdgcn_mfma_f32_16x16x32_bf16(
                        a_hi[t], b_hi, acc[t][i], 0, 0, 0);
                    acc[t][i] = __builtin_amdgcn_mfma_f32_16x16x32_bf16(
                        a_lo[t], b_hi, acc[t][i], 0, 0, 0);
                    acc[t][i] = __builtin_amdgcn_mfma_f32_16x16x32_bf16(
                        a_hi[t], b_lo, acc[t][i], 0, 0, 0);
                }
            }
        }
    }

#pragma unroll
    for (int i = 0; i < 5; ++i) {
        const int nt = wt + 4 * i;
        if (nt < 18) {
            const int col = nt * 16 + c;
#pragma unroll
            for (int t = 0; t < 2; ++t)
#pragma unroll
                for (int j = 0; j < 4; ++j)
                    logits[(size_t)(row0 + t * 16 + 4 * g + j) * 288 + col] =
                        acc[t][i][j];
        }
    }
}

// ---------------------------------------------------------------------------
// K3: sampler, cooperative epilogue (R14) + XCD-aware 1D grid (R15).
// ---------------------------------------------------------------------------
__global__ __launch_bounds__(256) void sample_kernel(
    const float* __restrict__ logits,
    const float* __restrict__ ref,
    const float* __restrict__ boff, const float* __restrict__ battn,
    const unsigned short* __restrict__ v0,
    const unsigned short* __restrict__ v1,
    const unsigned short* __restrict__ v2,
    unsigned short* __restrict__ outp)
{
    const int tid  = threadIdx.x;
    const int wv   = tid >> 6;
    const int lane = tid & 63;
    const int qd   = lane >> 3;
    const int co   = lane & 7;

    const int id = blockIdx.x;           // 0..10015
    const int h  = id & 7;               // XCD key
    const int m  = id >> 3;              // 0..1251
    const int b  = m / 313;
    const int n  = m - b * 313;
    const int q  = n * 32 + wv * 8 + qd;
    if (q >= QLEN) return;               // whole 8-lane group exits together
    const int qq = b * QLEN + q;

    const float* lgq  = logits + (size_t)qq * 288;
    const int bpbase  = (lane & 56) * 4;     // byte index of group lane 0

    // ---- distributed softmax over the 12 attn logits ----
    const float at0 = lgq[192 + h * 12 + co] + battn[h * 12 + co];
    const float at1 = (co < 4)
        ? lgq[192 + h * 12 + 8 + co] + battn[h * 12 + 8 + co] : -1e30f;
    float mx = fmaxf(at0, at1);
#pragma unroll
    for (int msk = 1; msk < 8; msk <<= 1)
        mx = fmaxf(mx, __shfl_xor(mx, msk, 8));
    const float e0 = __expf(at0 - mx);
    const float e1 = (co < 4) ? __expf(at1 - mx) : 0.f;
    float sm = e0 + e1;
#pragma unroll
    for (int msk = 1; msk < 8; msk <<= 1)
        sm += __shfl_xor(sm, msk, 8);
    const float inv = 1.f / sm;

    const float refx = ref[(size_t)qq * 2 + 0];
    const float refy = ref[(size_t)qq * 2 + 1];

    // ---- owner: corner data for points co (slot 0) and co+8 (slot 1) ----
    int   oidx[2][4];
    float owt [2][4];
#pragma unroll
    for (int s = 0; s < 2; ++s) {
        const int pt = co + 8 * s;                   // slot1 valid only co<4
        const int l  = (s == 0) ? (co >> 2) : 2;
        const int Wl = (l == 0) ? 100 : (l == 1) ? 50 : 25;
        const float aw  = (s ? e1 : e0) * inv;
        const float lgx = lgq[h * 24 + 2 * pt]     + boff[h * 24 + 2 * pt];
        const float lgy = lgq[h * 24 + 2 * pt + 1] + boff[h * 24 + 2 * pt + 1];
        const float x = (refx + 0.5f * tanh_fast(lgx)) * (float)Wl - 0.5f;
        const float y = (refy + 0.5f * tanh_fast(lgy)) * (float)Wl - 0.5f;
        const float xf = floorf(x), yf = floorf(y);
        const int   x0i = (int)xf, y0i = (int)yf;
        const float wx = x - xf, wy = y - yf;
#pragma unroll
        for (int cy = 0; cy < 2; ++cy) {
#pragma unroll
            for (int cx = 0; cx < 2; ++cx) {
                const int xi = x0i + cx, yi = y0i + cy;
                const bool valid = (xi >= 0) & (xi < Wl) & (yi >= 0) & (yi < Wl);
                const int xc = min(max(xi, 0), Wl - 1);
                const int yc = min(max(yi, 0), Wl - 1);
                oidx[s][cy * 2 + cx] = yc * Wl + xc;
                owt [s][cy * 2 + cx] = valid
                    ? aw * (cx ? wx : 1.f - wx) * (cy ? wy : 1.f - wy) : 0.f;
            }
        }
    }

    // ---- gather: per level, broadcast owners' corner data via bpermute ----
    float o0 = 0.f, o1 = 0.f, o2 = 0.f, o3 = 0.f;

#pragma unroll
    for (int l = 0; l < 3; ++l) {
        const int Wl = (l == 0) ? 100 : (l == 1) ? 50 : 25;
        const int HW = Wl * Wl;
        const unsigned short* vh =
            ((l == 0) ? v0 : (l == 1) ? v1 : v2) +
            ((size_t)(b * NHEAD + h) * HW) * 32;

#pragma unroll
        for (int p = 0; p < 4; ++p) {
            const int src  = (l == 2) ? p : l * 4 + p;
            const int slot = (l == 2) ? 1 : 0;
#pragma unroll
            for (int k = 0; k < 4; ++k) {
                const int ci = __builtin_amdgcn_ds_bpermute(
                    bpbase + 4 * src, oidx[slot][k]);
                const int cwbits = __builtin_amdgcn_ds_bpermute(
                    bpbase + 4 * src, __float_as_int(owt[slot][k]));
                const float cw = __int_as_float(cwbits);
                const ushort4 u = *(const ushort4*)(vh + (size_t)ci * 32 + co * 4);
                o0 = fmaf(cw, bf2f(u.x), o0);
                o1 = fmaf(cw, bf2f(u.y), o1);
                o2 = fmaf(cw, bf2f(u.z), o2);
                o3 = fmaf(cw, bf2f(u.w), o3);
            }
        }
    }

    unsigned int lo = (unsigned int)f2bf(o0) | ((unsigned int)f2bf(o1) << 16);
    unsigned int hi = (unsigned int)f2bf(o2) | ((unsigned int)f2bf(o3) << 16);
    *(uint2*)(outp + (size_t)qq * 256 + h * 32 + co * 4) = make_uint2(lo, hi);
}

// ---------------------------------------------------------------------------
// K4: output projection via bf16 MFMA (validated R7).
// ---------------------------------------------------------------------------
__global__ __launch_bounds__(256) void outproj_kernel(
    const unsigned short* __restrict__ A, const unsigned short* __restrict__ WoT,
    const float* __restrict__ bo, float* __restrict__ out)
{
    const int tid  = threadIdx.x;
    const int wave = tid >> 6;
    const int lane = tid & 63;
    const int c    = lane & 15;
    const int g    = lane >> 4;
    const int row0 = blockIdx.x * 64;
    const int n0   = wave * 64;

    f32x4 acc[4][4];
#pragma unroll
    for (int mt = 0; mt < 4; ++mt)
#pragma unroll
        for (int nt = 0; nt < 4; ++nt)
            acc[mt][nt] = (f32x4){0.f, 0.f, 0.f, 0.f};

    const unsigned short* Abase = A   + (size_t)(row0 + c) * 256 + 8 * g;
    const unsigned short* Bbase = WoT + (size_t)(n0   + c) * 256 + 8 * g;

#pragma unroll
    for (int ks = 0; ks < 8; ++ks) {
        bf16x8 a[4], bvec[4];
#pragma unroll
        for (int t = 0; t < 4; ++t) {
            a[t]    = *(const bf16x8*)(Abase + (size_t)t * 16 * 256 + ks * 32);
            bvec[t] = *(const bf16x8*)(Bbase + (size_t)t * 16 * 256 + ks * 32);
        }
#pragma unroll
        for (int mt = 0; mt < 4; ++mt)
#pragma unroll
            for (int nt = 0; nt < 4; ++nt)
                acc[mt][nt] = __builtin_amdgcn_mfma_f32_16x16x32_bf16(
                    a[mt], bvec[nt], acc[mt][nt], 0, 0, 0);
    }

#pragma unroll
    for (int nt = 0; nt < 4; ++nt) {
        const int col  = n0 + nt * 16 + c;
        const float bias = bo[col];
#pragma unroll
        for (int mt = 0; mt < 4; ++mt) {
#pragma unroll
            for (int j = 0; j < 4; ++j) {
                const int row = row0 + mt * 16 + g * 4 + j;
                out[(size_t)row * 256 + col] = acc[mt][nt][j] + bias;
            }
        }
    }
}

// ---------------------------------------------------------------------------
extern "C" void kernel_launch(void* const* d_in, const int* in_sizes, int n_in,
                              void* d_out, int out_size, void* d_ws, size_t ws_size,
                              hipStream_t stream)
{
    const float* query  = (const float*)d_in[0];
    const float* value0 = (const float*)d_in[1];
    const float* value1 = (const float*)d_in[2];
    const float* value2 = (const float*)d_in[3];
    const float* refpts = (const float*)d_in[4];
    const float* Woff   = (const float*)d_in[5];
    const float* boff   = (const float*)d_in[6];
    const float* Wattn  = (const float*)d_in[7];
    const float* battn  = (const float*)d_in[8];
    const float* Wval   = (const float*)d_in[9];
    const float* bval   = (const float*)d_in[10];
    const float* Wout   = (const float*)d_in[11];
    const float* bout   = (const float*)d_in[12];
    float* out = (float*)d_out;

    // workspace: logits 46.08 + v 26.88 + A_bf 20.48 + weights ~0.7 = ~94.2 MB
    float*          logits = (float*)d_ws;
    unsigned short* v0   = (unsigned short*)(logits + (size_t)NQ * 288);
    unsigned short* v1   = v0 + (size_t)BATCH * 10000 * 256;
    unsigned short* v2   = v1 + (size_t)BATCH * 2500  * 256;
    unsigned short* A_bf = v2 + (size_t)BATCH * 625   * 256;
    unsigned short* WoT  = A_bf + (size_t)NQ * 256;
    unsigned short* WTs  = WoT + (size_t)256 * 256;        // 147456 shorts
    unsigned short* WvSh = WTs + (size_t)147456;
    unsigned short* WvSl = WvSh + (size_t)65536;

    wprep_kernel<<<800, 256, 0, stream>>>(Woff, Wattn, Wout, Wval,
                                          WTs, WoT, WvSh, WvSl);

    vproj_kernel<<<dim3(412, BATCH), 256, 0, stream>>>(
        value0, value1, value2, WvSh, WvSl, bval, v0, v1, v2);

    qgemm_kernel<<<NQ / 32, 256, 0, stream>>>(query, WTs, logits);

    sample_kernel<<<8 * 313 * BATCH, 256, 0, stream>>>(
        logits, refpts, boff, battn, v0, v1, v2, A_bf);

    outproj_kernel<<<NQ / 64, 256, 0, stream>>>(A_bf, WoT, bout, out);
}

// Round 20
// 196.295 us; speedup vs baseline: 1.2594x; 1.0142x over previous
//
#include <hip/hip_runtime.h>
#include <math.h>

#define DMODEL 256
#define NHEAD 8
#define NLVL 3
#define NPTS 4
#define HDIM 32
#define QLEN 10000
#define BATCH 4
#define NQ (BATCH * QLEN)

typedef __attribute__((ext_vector_type(8))) short bf16x8;
typedef __attribute__((ext_vector_type(4))) float f32x4;

__device__ __forceinline__ float tanh_fast(float x)
{
    const float ax = fabsf(x);
    const float e  = __expf(-2.f * ax);
    const float t  = (1.f - e) / (1.f + e);
    return copysignf(t, x);
}

__device__ __forceinline__ unsigned short f2bf(float f)
{
    unsigned int u = __float_as_uint(f);
    u = (u + 0x7FFFu + ((u >> 16) & 1u)) >> 16;
    return (unsigned short)u;
}

__device__ __forceinline__ float bf2f(unsigned short s)
{
    return __uint_as_float(((unsigned int)s) << 16);
}

// ---------------------------------------------------------------------------
// K0: weight prep (once).  Pre-swizzled layouts (validated R18):
//   WTs : [ks][hl][nt][g][c][8]   (qgemm B, hi+lo)   147456 shorts
//   WoT : [n][k] bf16             (outproj B)         65536 shorts
//   WvS : [nc][ks][g][c][8]       (vproj B, hi & lo)  65536 shorts each
// ---------------------------------------------------------------------------
__global__ __launch_bounds__(256) void wprep_kernel(
    const float* __restrict__ Woff, const float* __restrict__ Wattn,
    const float* __restrict__ Wout, const float* __restrict__ Wval,
    unsigned short* __restrict__ WTs, unsigned short* __restrict__ WoT,
    unsigned short* __restrict__ WvSh, unsigned short* __restrict__ WvSl)
{
    const int k  = threadIdx.x;
    const int n  = blockIdx.x;
    const int ks = k >> 5;
    const int g  = (k >> 3) & 3;
    const int j  = k & 7;
    if (n < 288) {
        const float w = (n < 192) ? Woff[(size_t)k * 192 + n]
                                  : Wattn[(size_t)k * 96 + (n - 192)];
        const unsigned short hi = f2bf(w);
        const unsigned short lo = f2bf(w - bf2f(hi));
        const int nt = n >> 4, c = n & 15;
        const size_t base = (size_t)ks * 18432 + (size_t)nt * 512
                          + g * 128 + c * 8 + j;
        WTs[base]        = hi;    // hl = 0
        WTs[base + 9216] = lo;    // hl = 1 (offset 9216 shorts)
    } else if (n < 544) {
        const int nn = n - 288;
        WoT[(size_t)nn * 256 + k] = f2bf(Wout[(size_t)k * 256 + nn]);
    } else {
        const int nn = n - 544;
        const float w = Wval[(size_t)k * 256 + nn];
        const unsigned short hi = f2bf(w);
        const int nc = nn >> 4, c = nn & 15;
        const size_t idx = (size_t)nc * 4096 + (size_t)ks * 512
                         + g * 128 + c * 8 + j;
        WvSh[idx] = hi;
        WvSl[idx] = f2bf(w - bf2f(hi));
    }
}

// ---------------------------------------------------------------------------
// K1: value projection via bf16 MFMA, 32-pos tiles (validated R18).
// Output HEAD-MAJOR v[b][h][pos][32].
// ---------------------------------------------------------------------------
__global__ __launch_bounds__(256) void vproj_kernel(
    const float* __restrict__ feat0, const float* __restrict__ feat1,
    const float* __restrict__ feat2,
    const unsigned short* __restrict__ WvSh, const unsigned short* __restrict__ WvSl,
    const float* __restrict__ bv,
    unsigned short* __restrict__ v0, unsigned short* __restrict__ v1,
    unsigned short* __restrict__ v2)
{
    __shared__ short As[32 * 32 * 8];   // [kc][pos][8] = 16 KB

    const int bx = blockIdx.x;
    const int b  = blockIdx.y;

    const float* feat;
    unsigned short* vout;
    int HW, pos0;
    if (bx < 313)      { feat = feat0; vout = v0; HW = 10000; pos0 = bx * 32; }
    else if (bx < 392) { feat = feat1; vout = v1; HW = 2500;  pos0 = (bx - 313) * 32; }
    else               { feat = feat2; vout = v2; HW = 625;   pos0 = (bx - 392) * 32; }

    const int tid  = threadIdx.x;
    const int wv   = tid >> 6;
    const int lane = tid & 63;
    const int c    = lane & 15;
    const int g    = lane >> 4;

    const int sp  = tid & 31;
    const int kc8 = tid >> 5;
    const bool pv = (pos0 + sp) < HW;
    const float* fcol = feat + (size_t)b * DMODEL * HW + pos0 + sp;

#pragma unroll
    for (int i = 0; i < 4; ++i) {
        const int kc = kc8 + 8 * i;
        short h8[8];
#pragma unroll
        for (int j = 0; j < 8; ++j) {
            const float f = pv ? fcol[(size_t)(kc * 8 + j) * HW] : 0.f;
            h8[j] = (short)f2bf(f);
        }
        *(bf16x8*)&As[((size_t)kc * 32 + sp) * 8] = *(bf16x8*)h8;
    }
    __syncthreads();

    f32x4 acc[2][4];
#pragma unroll
    for (int mt = 0; mt < 2; ++mt)
#pragma unroll
        for (int nt = 0; nt < 4; ++nt)
            acc[mt][nt] = (f32x4){0.f, 0.f, 0.f, 0.f};

#pragma unroll
    for (int ks = 0; ks < 8; ++ks) {
        bf16x8 a[2];
#pragma unroll
        for (int mt = 0; mt < 2; ++mt)
            a[mt] = *(const bf16x8*)&As[((size_t)(ks * 4 + g) * 32 + mt * 16 + c) * 8];
        bf16x8 bh[4], bl[4];
#pragma unroll
        for (int nt = 0; nt < 4; ++nt) {
            const size_t off = (size_t)(wv * 4 + nt) * 4096 + (size_t)ks * 512
                             + g * 128 + c * 8;
            bh[nt] = *(const bf16x8*)(WvSh + off);
            bl[nt] = *(const bf16x8*)(WvSl + off);
        }
#pragma unroll
        for (int mt = 0; mt < 2; ++mt)
#pragma unroll
            for (int nt = 0; nt < 4; ++nt) {
                acc[mt][nt] = __builtin_amdgcn_mfma_f32_16x16x32_bf16(
                    a[mt], bh[nt], acc[mt][nt], 0, 0, 0);
                acc[mt][nt] = __builtin_amdgcn_mfma_f32_16x16x32_bf16(
                    a[mt], bl[nt], acc[mt][nt], 0, 0, 0);
            }
    }

    unsigned short* vbp = vout + (size_t)b * NHEAD * HW * 32;
#pragma unroll
    for (int nt = 0; nt < 4; ++nt) {
        const int col  = wv * 64 + nt * 16 + c;
        const int hh   = col >> 5;
        const int cc   = col & 31;
        const float bias = bv[col];
#pragma unroll
        for (int mt = 0; mt < 2; ++mt) {
#pragma unroll
            for (int j = 0; j < 4; ++j) {
                const int p = mt * 16 + g * 4 + j;
                if (pos0 + p < HW)
                    vbp[((size_t)hh * HW + pos0 + p) * 32 + cc] =
                        f2bf(acc[mt][nt][j] + bias);
            }
        }
    }
}

// ---------------------------------------------------------------------------
// K2: query-side GEMM, direct-global B (validated R19).  No LDS, no barriers.
// ---------------------------------------------------------------------------
__global__ __launch_bounds__(256) void qgemm_kernel(
    const float* __restrict__ query,
    const unsigned short* __restrict__ WTs,
    float* __restrict__ logits)
{
    const int tid  = threadIdx.x;
    const int wt   = tid >> 6;
    const int lane = tid & 63;
    const int c    = lane & 15;
    const int g    = lane >> 4;
    const int row0 = blockIdx.x * 32;

    const float* qr[2];
#pragma unroll
    for (int t = 0; t < 2; ++t)
        qr[t] = query + (size_t)(row0 + t * 16 + c) * 256 + 8 * g;

    f32x4 acc[2][5];
#pragma unroll
    for (int t = 0; t < 2; ++t)
#pragma unroll
        for (int i = 0; i < 5; ++i) acc[t][i] = (f32x4){0.f, 0.f, 0.f, 0.f};

#pragma unroll
    for (int ks = 0; ks < 8; ++ks) {
        bf16x8 a_hi[2], a_lo[2];
#pragma unroll
        for (int t = 0; t < 2; ++t) {
            const float4 q0 = *(const float4*)(qr[t] + ks * 32);
            const float4 q1 = *(const float4*)(qr[t] + ks * 32 + 4);
            const float av[8] = {q0.x, q0.y, q0.z, q0.w, q1.x, q1.y, q1.z, q1.w};
#pragma unroll
            for (int j = 0; j < 8; ++j) {
                const unsigned short hi = f2bf(av[j]);
                a_hi[t][j] = (short)hi;
                a_lo[t][j] = (short)f2bf(av[j] - bf2f(hi));
            }
        }

#pragma unroll
        for (int i = 0; i < 5; ++i) {
            const int nt = wt + 4 * i;
            if (nt < 18) {
                const unsigned short* bp = WTs + (size_t)ks * 18432
                                         + (size_t)nt * 512 + g * 128 + c * 8;
                const bf16x8 b_hi = *(const bf16x8*)bp;
                const bf16x8 b_lo = *(const bf16x8*)(bp + 9216);
#pragma unroll
                for (int t = 0; t < 2; ++t) {
                    acc[t][i] = __builtin_amdgcn_mfma_f32_16x16x32_bf16(
                        a_hi[t], b_hi, acc[t][i], 0, 0, 0);
                    acc[t][i] = __builtin_amdgcn_mfma_f32_16x16x32_bf16(
                        a_lo[t], b_hi, acc[t][i], 0, 0, 0);
                    acc[t][i] = __builtin_amdgcn_mfma_f32_16x16x32_bf16(
                        a_hi[t], b_lo, acc[t][i], 0, 0, 0);
                }
            }
        }
    }

#pragma unroll
    for (int i = 0; i < 5; ++i) {
        const int nt = wt + 4 * i;
        if (nt < 18) {
            const int col = nt * 16 + c;
#pragma unroll
            for (int t = 0; t < 2; ++t)
#pragma unroll
                for (int j = 0; j < 4; ++j)
                    logits[(size_t)(row0 + t * 16 + 4 * g + j) * 288 + col] =
                        acc[t][i][j];
        }
    }
}

// ---------------------------------------------------------------------------
// K3: sampler, cooperative epilogue (R14) + XCD grid (R15) + PACKED
// single-bpermute corner broadcast: (bf16-weight << 16) | idx16.  Corner
// index < 10000 fits 16 bits; the high half IS the f32 weight bit pattern
// (bf16 in high 16, zeros low) -> unpack = 2 ANDs.  Halves LDS-pipe traffic.
// ---------------------------------------------------------------------------
__global__ __launch_bounds__(256) void sample_kernel(
    const float* __restrict__ logits,
    const float* __restrict__ ref,
    const float* __restrict__ boff, const float* __restrict__ battn,
    const unsigned short* __restrict__ v0,
    const unsigned short* __restrict__ v1,
    const unsigned short* __restrict__ v2,
    unsigned short* __restrict__ outp)
{
    const int tid  = threadIdx.x;
    const int wv   = tid >> 6;
    const int lane = tid & 63;
    const int qd   = lane >> 3;
    const int co   = lane & 7;

    const int id = blockIdx.x;           // 0..10015
    const int h  = id & 7;               // XCD key
    const int m  = id >> 3;              // 0..1251
    const int b  = m / 313;
    const int n  = m - b * 313;
    const int q  = n * 32 + wv * 8 + qd;
    if (q >= QLEN) return;               // whole 8-lane group exits together
    const int qq = b * QLEN + q;

    const float* lgq  = logits + (size_t)qq * 288;
    const int bpbase  = (lane & 56) * 4;     // byte index of group lane 0

    // ---- distributed softmax over the 12 attn logits ----
    const float at0 = lgq[192 + h * 12 + co] + battn[h * 12 + co];
    const float at1 = (co < 4)
        ? lgq[192 + h * 12 + 8 + co] + battn[h * 12 + 8 + co] : -1e30f;
    float mx = fmaxf(at0, at1);
#pragma unroll
    for (int msk = 1; msk < 8; msk <<= 1)
        mx = fmaxf(mx, __shfl_xor(mx, msk, 8));
    const float e0 = __expf(at0 - mx);
    const float e1 = (co < 4) ? __expf(at1 - mx) : 0.f;
    float sm = e0 + e1;
#pragma unroll
    for (int msk = 1; msk < 8; msk <<= 1)
        sm += __shfl_xor(sm, msk, 8);
    const float inv = 1.f / sm;

    const float refx = ref[(size_t)qq * 2 + 0];
    const float refy = ref[(size_t)qq * 2 + 1];

    // ---- owner: packed (bf16 weight | idx) for points co, co+8(co<4) ----
    unsigned int opk[2][4];
#pragma unroll
    for (int s = 0; s < 2; ++s) {
        const int pt = co + 8 * s;                   // slot1 valid only co<4
        const int l  = (s == 0) ? (co >> 2) : 2;
        const int Wl = (l == 0) ? 100 : (l == 1) ? 50 : 25;
        const float aw  = (s ? e1 : e0) * inv;
        const float lgx = lgq[h * 24 + 2 * pt]     + boff[h * 24 + 2 * pt];
        const float lgy = lgq[h * 24 + 2 * pt + 1] + boff[h * 24 + 2 * pt + 1];
        const float x = (refx + 0.5f * tanh_fast(lgx)) * (float)Wl - 0.5f;
        const float y = (refy + 0.5f * tanh_fast(lgy)) * (float)Wl - 0.5f;
        const float xf = floorf(x), yf = floorf(y);
        const int   x0i = (int)xf, y0i = (int)yf;
        const float wx = x - xf, wy = y - yf;
#pragma unroll
        for (int cy = 0; cy < 2; ++cy) {
#pragma unroll
            for (int cx = 0; cx < 2; ++cx) {
                const int xi = x0i + cx, yi = y0i + cy;
                const bool valid = (xi >= 0) & (xi < Wl) & (yi >= 0) & (yi < Wl);
                const int xc = min(max(xi, 0), Wl - 1);
                const int yc = min(max(yi, 0), Wl - 1);
                const float w = valid
                    ? aw * (cx ? wx : 1.f - wx) * (cy ? wy : 1.f - wy) : 0.f;
                opk[s][cy * 2 + cx] =
                    ((unsigned int)f2bf(w) << 16) | (unsigned int)(yc * Wl + xc);
            }
        }
    }

    // ---- gather: one bpermute per corner, unpack = 2 ANDs ----
    float o0 = 0.f, o1 = 0.f, o2 = 0.f, o3 = 0.f;

#pragma unroll
    for (int l = 0; l < 3; ++l) {
        const int Wl = (l == 0) ? 100 : (l == 1) ? 50 : 25;
        const int HW = Wl * Wl;
        const unsigned short* vh =
            ((l == 0) ? v0 : (l == 1) ? v1 : v2) +
            ((size_t)(b * NHEAD + h) * HW) * 32;

#pragma unroll
        for (int p = 0; p < 4; ++p) {
            const int src  = (l == 2) ? p : l * 4 + p;
            const int slot = (l == 2) ? 1 : 0;
#pragma unroll
            for (int k = 0; k < 4; ++k) {
                const unsigned int pk = (unsigned int)__builtin_amdgcn_ds_bpermute(
                    bpbase + 4 * src, (int)opk[slot][k]);
                const float cw = __uint_as_float(pk & 0xffff0000u);
                const int   ci = (int)(pk & 0xffffu);
                const ushort4 u = *(const ushort4*)(vh + (size_t)ci * 32 + co * 4);
                o0 = fmaf(cw, bf2f(u.x), o0);
                o1 = fmaf(cw, bf2f(u.y), o1);
                o2 = fmaf(cw, bf2f(u.z), o2);
                o3 = fmaf(cw, bf2f(u.w), o3);
            }
        }
    }

    unsigned int lo = (unsigned int)f2bf(o0) | ((unsigned int)f2bf(o1) << 16);
    unsigned int hi = (unsigned int)f2bf(o2) | ((unsigned int)f2bf(o3) << 16);
    *(uint2*)(outp + (size_t)qq * 256 + h * 32 + co * 4) = make_uint2(lo, hi);
}

// ---------------------------------------------------------------------------
// K4: output projection via bf16 MFMA (validated R7).
// ---------------------------------------------------------------------------
__global__ __launch_bounds__(256) void outproj_kernel(
    const unsigned short* __restrict__ A, const unsigned short* __restrict__ WoT,
    const float* __restrict__ bo, float* __restrict__ out)
{
    const int tid  = threadIdx.x;
    const int wave = tid >> 6;
    const int lane = tid & 63;
    const int c    = lane & 15;
    const int g    = lane >> 4;
    const int row0 = blockIdx.x * 64;
    const int n0   = wave * 64;

    f32x4 acc[4][4];
#pragma unroll
    for (int mt = 0; mt < 4; ++mt)
#pragma unroll
        for (int nt = 0; nt < 4; ++nt)
            acc[mt][nt] = (f32x4){0.f, 0.f, 0.f, 0.f};

    const unsigned short* Abase = A   + (size_t)(row0 + c) * 256 + 8 * g;
    const unsigned short* Bbase = WoT + (size_t)(n0   + c) * 256 + 8 * g;

#pragma unroll
    for (int ks = 0; ks < 8; ++ks) {
        bf16x8 a[4], bvec[4];
#pragma unroll
        for (int t = 0; t < 4; ++t) {
            a[t]    = *(const bf16x8*)(Abase + (size_t)t * 16 * 256 + ks * 32);
            bvec[t] = *(const bf16x8*)(Bbase + (size_t)t * 16 * 256 + ks * 32);
        }
#pragma unroll
        for (int mt = 0; mt < 4; ++mt)
#pragma unroll
            for (int nt = 0; nt < 4; ++nt)
                acc[mt][nt] = __builtin_amdgcn_mfma_f32_16x16x32_bf16(
                    a[mt], bvec[nt], acc[mt][nt], 0, 0, 0);
    }

#pragma unroll
    for (int nt = 0; nt < 4; ++nt) {
        const int col  = n0 + nt * 16 + c;
        const float bias = bo[col];
#pragma unroll
        for (int mt = 0; mt < 4; ++mt) {
#pragma unroll
            for (int j = 0; j < 4; ++j) {
                const int row = row0 + mt * 16 + g * 4 + j;
                out[(size_t)row * 256 + col] = acc[mt][nt][j] + bias;
            }
        }
    }
}

// ---------------------------------------------------------------------------
extern "C" void kernel_launch(void* const* d_in, const int* in_sizes, int n_in,
                              void* d_out, int out_size, void* d_ws, size_t ws_size,
                              hipStream_t stream)
{
    const float* query  = (const float*)d_in[0];
    const float* value0 = (const float*)d_in[1];
    const float* value1 = (const float*)d_in[2];
    const float* value2 = (const float*)d_in[3];
    const float* refpts = (const float*)d_in[4];
    const float* Woff   = (const float*)d_in[5];
    const float* boff   = (const float*)d_in[6];
    const float* Wattn  = (const float*)d_in[7];
    const float* battn  = (const float*)d_in[8];
    const float* Wval   = (const float*)d_in[9];
    const float* bval   = (const float*)d_in[10];
    const float* Wout   = (const float*)d_in[11];
    const float* bout   = (const float*)d_in[12];
    float* out = (float*)d_out;

    // workspace: logits 46.08 + v 26.88 + A_bf 20.48 + weights ~0.7 = ~94.2 MB
    float*          logits = (float*)d_ws;
    unsigned short* v0   = (unsigned short*)(logits + (size_t)NQ * 288);
    unsigned short* v1   = v0 + (size_t)BATCH * 10000 * 256;
    unsigned short* v2   = v1 + (size_t)BATCH * 2500  * 256;
    unsigned short* A_bf = v2 + (size_t)BATCH * 625   * 256;
    unsigned short* WoT  = A_bf + (size_t)NQ * 256;
    unsigned short* WTs  = WoT + (size_t)256 * 256;        // 147456 shorts
    unsigned short* WvSh = WTs + (size_t)147456;
    unsigned short* WvSl = WvSh + (size_t)65536;

    wprep_kernel<<<800, 256, 0, stream>>>(Woff, Wattn, Wout, Wval,
                                          WTs, WoT, WvSh, WvSl);

    vproj_kernel<<<dim3(412, BATCH), 256, 0, stream>>>(
        value0, value1, value2, WvSh, WvSl, bval, v0, v1, v2);

    qgemm_kernel<<<NQ / 32, 256, 0, stream>>>(query, WTs, logits);

    sample_kernel<<<8 * 313 * BATCH, 256, 0, stream>>>(
        logits, refpts, boff, battn, v0, v1, v2, A_bf);

    outproj_kernel<<<NQ / 64, 256, 0, stream>>>(A_bf, WoT, bout, out);
}